// Round 19
// baseline (248.432 us; speedup 1.0000x reference)
//
#include <hip/hip_runtime.h>
#include <hip/hip_bf16.h>

#define BB 8
#define NN 2048
#define DP 64
#define DM 512
#define KNNK 16
#define ROWS (BB*NN)   // 16384

// pre-swizzled staging chunk for thread t (pairs with RCH8 read swizzle) -- 32-short rows
#define SWZ_SK8(t) (((((t)&3) ^ (((t)>>3)&3)))*8)

typedef __attribute__((ext_vector_type(8))) short s16x8;
typedef __attribute__((ext_vector_type(4))) short s16x4;
typedef __attribute__((ext_vector_type(4))) float f32x4;

__device__ __forceinline__ float bf2f(short u){
  union { unsigned int i; float f; } v; v.i = ((unsigned int)(unsigned short)u) << 16; return v.f;
}
__device__ __forceinline__ short f2bf(float f){
  __hip_bfloat16 h = __float2bfloat16(f);    // RNE; compiler can pack pairs via v_cvt_pk_bf16_f32
  return *reinterpret_cast<short*>(&h);
}

// global -> LDS direct (16B per lane)
__device__ __forceinline__ void gload16(const void* g, void* l){
  __builtin_amdgcn_global_load_lds(
      (const __attribute__((address_space(1))) void*)(__UINTPTR_TYPE__)g,
      (__attribute__((address_space(3))) void*)(__UINTPTR_TYPE__)l, 16, 0, 0);
}

// wave-wide min of u32 via DPP (row_shr 1/2/4/8, row_bcast 15/31), broadcast via readlane
__device__ __forceinline__ unsigned wave_min_u32(unsigned v){
  v = min(v, (unsigned)__builtin_amdgcn_update_dpp((int)v, (int)v, 0x111, 0xF, 0xF, false));
  v = min(v, (unsigned)__builtin_amdgcn_update_dpp((int)v, (int)v, 0x112, 0xF, 0xF, false));
  v = min(v, (unsigned)__builtin_amdgcn_update_dpp((int)v, (int)v, 0x114, 0xF, 0xF, false));
  v = min(v, (unsigned)__builtin_amdgcn_update_dpp((int)v, (int)v, 0x118, 0xF, 0xF, false));
  v = min(v, (unsigned)__builtin_amdgcn_update_dpp((int)v, (int)v, 0x142, 0xF, 0xF, false));
  v = min(v, (unsigned)__builtin_amdgcn_update_dpp((int)v, (int)v, 0x143, 0xF, 0xF, false));
  return (unsigned)__builtin_amdgcn_readlane((int)v, 63);
}

// ---------------- exact knn (sq fused): wave-per-row, packed keys, top-3 tournament ----------------
__global__ __launch_bounds__(256) void k_knn(const float* __restrict__ xyz,
        int* __restrict__ kidx, float* __restrict__ kw, float* __restrict__ wsum){
  int row = blockIdx.x*4 + (threadIdx.x >> 6);
  int l = threadIdx.x & 63;
  int b = row >> 11; int i = row & (NN-1);
  const float* xb = xyz + (size_t)b*NN*3;
  float xi0 = xb[3*i], xi1 = xb[3*i+1], xi2 = xb[3*i+2];
  float sqi = xi0*xi0 + xi1*xi1 + xi2*xi2;
  unsigned key[32];
  unsigned m1 = 0xFFFFFFFFu, m2 = 0xFFFFFFFFu, m3 = 0xFFFFFFFFu;
  #pragma unroll
  for (int e = 0; e < 32; ++e){
    int j = e*64 + l;
    float x0 = xb[3*j], x1 = xb[3*j+1], x2 = xb[3*j+2];
    float sqj = x0*x0 + x1*x1 + x2*x2;
    float d = sqi + sqj - 2.0f*(xi0*x0 + xi1*x1 + xi2*x2);
    d = fmaxf(d, 0.f);
    union { float f; unsigned u; } cv; cv.f = d;
    unsigned k = (cv.u & 0xFFFFF800u) | (unsigned)j;
    key[e] = k;
    unsigned r1 = max(k, m1);  m1 = min(k, m1);
    unsigned r2 = max(r1, m2); m2 = min(r1, m2);
    m3 = min(r2, m3);
  }
  float wacc = 0.f;
  for (int sel = 0; sel < KNNK; ++sel){
    unsigned g = wave_min_u32(m1);          // uniform
    unsigned j = g & 2047u;
    union { unsigned u; float f; } dv; dv.u = g & 0xFFFFF800u;
    float wg = 1.0f/(dv.f + 1e-6f);
    wacc += wg;
    if (l == 0){
      kidx[(size_t)row*KNNK + sel] = (int)j;
      kw[(size_t)row*KNNK + sel] = wg;
    }
    bool win = (m1 == g);                   // at most one lane (keys unique)
    if (win){ m1 = m2; m2 = m3; m3 = 0xFFFFFFFFu; }
    if (__any(win && m1 == 0xFFFFFFFFu)){   // rare: winner exhausted its top-3
      if (win && m1 == 0xFFFFFFFFu){
        unsigned mm = 0xFFFFFFFFu;
        #pragma unroll
        for (int e = 0; e < 32; ++e){
          unsigned k2 = key[e];
          mm = min(mm, (k2 > g) ? k2 : 0xFFFFFFFFu);
        }
        m1 = mm;
      }
    }
  }
  if (l == 0) wsum[row] = wacc;
}

// ---------------- one-shot prep: transposed bf16 weights + featb ----------------
__global__ void k_prep2(const float* __restrict__ Wq, const float* __restrict__ Wk,
                        const float* __restrict__ Wv, const float* __restrict__ Wd2,
                        const float* __restrict__ W1, const float* __restrict__ W2,
                        const float* __restrict__ feat,
                        short* __restrict__ Wqt, short* __restrict__ Wkt,
                        short* __restrict__ Wvt, short* __restrict__ Wd2t,
                        short* __restrict__ W1t, short* __restrict__ W2t,
                        short* __restrict__ featb){
  int idx = blockIdx.x*256 + threadIdx.x;
  if (idx < 4*DM*DM){
    int m = idx >> 18;
    int r = idx & (DM*DM-1);
    int n = r >> 9, k = r & 511;
    const float* W = (m==0)?Wq:(m==1)?Wk:(m==2)?Wv:Wd2;
    short* Wt = (m==0)?Wqt:(m==1)?Wkt:(m==2)?Wvt:Wd2t;
    Wt[r] = f2bf(W[k*DM + n]);
  } else if (idx < 4*DM*DM + DM*DP){
    int r = idx - 4*DM*DM;
    int n = r >> 6, k = r & 63;
    W1t[r] = f2bf(W1[(size_t)k*DM + n]);
  } else if (idx < 4*DM*DM + 2*DM*DP){
    int r = idx - 4*DM*DM - DM*DP;
    int n = r >> 9, k = r & 511;
    W2t[r] = f2bf(W2[(size_t)k*DP + n]);
  } else {
    int r = idx - 4*DM*DM - 2*DM*DP;
    featb[r] = f2bf(feat[r]);
  }
}

// ---------------- g = (sum_j w_j * relu(xyz[idx_j]@Wd1 + bd1)) / wsum, fused, bf16 ----------------
__global__ __launch_bounds__(256) void k_g(const float* __restrict__ xyz, const float* __restrict__ Wd1,
                   const float* __restrict__ bd1, const int* __restrict__ kidx,
                   const float* __restrict__ kw, const float* __restrict__ wsum, short* __restrict__ g){
  int bid = blockIdx.x;
  int p = ((bid&7)<<11) + ((bid>>3)<<2) + (threadIdx.x>>6);   // batch = bid&7 (XCD-pinned)
  int c8 = (threadIdx.x&63)*8;
  int b = p >> 11;
  const float* xbase = xyz + (size_t)b*NN*3;
  float wd0[8], wd1v[8], wd2v[8], bb[8];
  #pragma unroll
  for (int e=0;e<8;++e){
    wd0[e]  = Wd1[c8+e];
    wd1v[e] = Wd1[DM + c8+e];
    wd2v[e] = Wd1[2*DM + c8+e];
    bb[e]   = bd1[c8+e];
  }
  int jj[KNNK]; float wj[KNNK];
  #pragma unroll
  for (int j = 0; j < KNNK; ++j){
    jj[j] = kidx[(size_t)p*KNNK + j];
    wj[j] = kw[(size_t)p*KNNK + j];
  }
  float acc[8] = {0,0,0,0,0,0,0,0};
  #pragma unroll
  for (int j = 0; j < KNNK; ++j){
    float x0 = xbase[3*jj[j]], x1 = xbase[3*jj[j]+1], x2 = xbase[3*jj[j]+2];
    float w = wj[j];
    #pragma unroll
    for (int e=0;e<8;++e){
      float v = fmaf(x0, wd0[e], fmaf(x1, wd1v[e], fmaf(x2, wd2v[e], bb[e])));
      acc[e] = fmaf(w, fmaxf(v, 0.f), acc[e]);
    }
  }
  float inv = 1.0f/wsum[p];
  s16x8 o;
  #pragma unroll
  for (int e=0;e<8;++e) o[e] = f2bf(acc[e]*inv);
  *(s16x8*)&g[(size_t)p*DM + c8] = o;
}

// ---------------- bf16 MFMA GEMM (BM=128,BN=128), XOR-swizzled LDS (BK=32) ----------------
template<int KD, int MODE>
__global__ __launch_bounds__(256) void k_gemm(const short* __restrict__ A, const short* __restrict__ Bt,
       const float* __restrict__ bias, const short* __restrict__ addb, short* __restrict__ outb){
  __shared__ short As[128*32];
  __shared__ short Bs[128*32];
  int t = threadIdx.x;
  size_t i0 = (size_t)blockIdx.x*128, n0 = (size_t)blockIdx.y*128;
  int w = t >> 6, l = t & 63, la = l & 15, lg = l >> 4;
  int wr = w >> 1, wc = w & 1;
  int rch8 = (lg ^ ((la>>1)&3))*8;
  f32x4 acc[4][4];
  #pragma unroll
  for (int h=0;h<4;++h)
    #pragma unroll
    for (int c=0;c<4;++c) acc[h][c] = (f32x4){0.f,0.f,0.f,0.f};
  int srow = t >> 2; int sk8 = SWZ_SK8(t);
  const short* Ab  = A  + (i0 + srow)*KD + sk8;
  const short* Ab2 = A  + (i0 + 64 + srow)*KD + sk8;
  const short* Bb  = Bt + (n0 + srow)*KD + sk8;
  const short* Bb2 = Bt + (n0 + 64 + srow)*KD + sk8;
  short* Asd  = &As[t*8];      short* Asd2 = &As[2048 + t*8];
  short* Bsd  = &Bs[t*8];      short* Bsd2 = &Bs[2048 + t*8];
  for (int k0 = 0; k0 < KD; k0 += 32){
    gload16(Ab  + k0, Asd);
    gload16(Ab2 + k0, Asd2);
    gload16(Bb  + k0, Bsd);
    gload16(Bb2 + k0, Bsd2);
    __syncthreads();
    s16x8 af[4], bg[4];
    #pragma unroll
    for (int h=0;h<4;++h) af[h] = *(const s16x8*)&As[(wr*64 + h*16 + la)*32 + rch8];
    #pragma unroll
    for (int c=0;c<4;++c) bg[c] = *(const s16x8*)&Bs[(wc*64 + c*16 + la)*32 + rch8];
    #pragma unroll
    for (int h=0;h<4;++h)
      #pragma unroll
      for (int c=0;c<4;++c)
        acc[h][c] = __builtin_amdgcn_mfma_f32_16x16x32_bf16(af[h], bg[c], acc[h][c], 0, 0, 0);
    __syncthreads();
  }
  #pragma unroll
  for (int h=0;h<4;++h){
    #pragma unroll
    for (int c=0;c<4;++c){
      size_t col = n0 + wc*64 + c*16 + la;
      #pragma unroll
      for (int r=0;r<4;++r){
        size_t row = i0 + wr*64 + h*16 + lg*4 + r;
        float v = acc[h][c][r];
        if (MODE == 0) outb[row*DM + col] = f2bf(v + bias[col]);
        else           outb[row*DM + col] = f2bf(v + bf2f(addb[row*DM + col]));
      }
    }
  }
}

// ---------------- merged QKV GEMM, 512 threads, BM=128 x BN=256 ----------------
__global__ __launch_bounds__(512) void k_gemm3(const short* __restrict__ A, const short* __restrict__ Bt,
       const short* __restrict__ addb, short* __restrict__ q, short* __restrict__ k, short* __restrict__ v){
  __shared__ short As[128*32];   // 8 KiB
  __shared__ short Bs[256*32];   // 16 KiB
  int t = threadIdx.x;
  int by = blockIdx.y;
  short* outb = (by < 2) ? q : (by < 4) ? k : v;
  size_t i0 = (size_t)blockIdx.x*128;
  size_t n0 = (size_t)by*256;          // row into 1536-row concat
  size_t c0 = (size_t)(by & 1)*256;    // output col base
  int w = t >> 6, l = t & 63, la = l & 15, lg = l >> 4;
  int wr = w >> 2, wc = w & 3;         // 2 x 4 waves: 64 rows x 64 cols each
  int rch8 = (lg ^ ((la>>1)&3))*8;
  f32x4 acc[4][4];
  #pragma unroll
  for (int h=0;h<4;++h)
    #pragma unroll
    for (int c=0;c<4;++c) acc[h][c] = (f32x4){0.f,0.f,0.f,0.f};
  int srow = t >> 2; int sk8 = SWZ_SK8(t);    // srow 0..127
  const short* Ab  = A  + (i0 + srow)*DM + sk8;
  const short* Bb  = Bt + (n0 + srow)*DM + sk8;
  const short* Bb2 = Bt + (n0 + 128 + srow)*DM + sk8;
  short* Asd = &As[t*8];
  short* Bsd = &Bs[t*8];  short* Bsd2 = &Bs[4096 + t*8];
  for (int k0 = 0; k0 < DM; k0 += 32){
    gload16(Ab  + k0, Asd);
    gload16(Bb  + k0, Bsd);
    gload16(Bb2 + k0, Bsd2);
    __syncthreads();
    s16x8 af[4], bg[4];
    #pragma unroll
    for (int h=0;h<4;++h) af[h] = *(const s16x8*)&As[(wr*64 + h*16 + la)*32 + rch8];
    #pragma unroll
    for (int c=0;c<4;++c) bg[c] = *(const s16x8*)&Bs[(wc*64 + c*16 + la)*32 + rch8];
    #pragma unroll
    for (int h=0;h<4;++h)
      #pragma unroll
      for (int c=0;c<4;++c)
        acc[h][c] = __builtin_amdgcn_mfma_f32_16x16x32_bf16(af[h], bg[c], acc[h][c], 0, 0, 0);
    __syncthreads();
  }
  #pragma unroll
  for (int h=0;h<4;++h){
    #pragma unroll
    for (int c=0;c<4;++c){
      size_t col = c0 + wc*64 + c*16 + la;
      #pragma unroll
      for (int r=0;r<4;++r){
        size_t row = i0 + wr*64 + h*16 + lg*4 + r;
        outb[row*DM + col] = f2bf(acc[h][c][r] + bf2f(addb[row*DM + col]));
      }
    }
  }
}

// ---------------- transpose ve -> vt[b][d][j] ----------------
__global__ __launch_bounds__(256) void k_vt(const short* __restrict__ ve, short* __restrict__ vt){
  int j0 = blockIdx.x*32, d0 = blockIdx.y*32, b = blockIdx.z;
  __shared__ short tile[32][36];
  int t = threadIdx.x;
  int r = t >> 3, c4 = (t & 7)*4;
  const short* vb = ve + (size_t)b*NN*DM;
  *(s16x4*)&tile[r][c4] = *(const s16x4*)&vb[(size_t)(j0+r)*DM + d0 + c4];
  __syncthreads();
  s16x4 o;
  #pragma unroll
  for (int e=0;e<4;++e) o[e] = tile[c4+e][r];
  short* ob = vt + (size_t)b*DM*NN;
  *(s16x4*)&ob[(size_t)(d0+r)*NN + j0 + c4] = o;
}

// ---------------- S-GEMM + exp, BK=64; P stored via LDS bounce -> 16B coalesced stores ----------------
__global__ __launch_bounds__(256) void k_sexp(const short* __restrict__ qe, const short* __restrict__ ke,
       short* __restrict__ pbuf, float* __restrict__ lsum_part){
  __shared__ short S[2*128*64];   // 32 KiB: As | Bs, reused as 128x128 bounce in epilogue
  short* As = S;
  short* Bs = S + 128*64;
  int bid = blockIdx.x;
  int b = bid & 7;
  int r2 = bid >> 3;                 // 0..255
  int ti = r2 & 15, tj = r2 >> 4;    // 16 i-tiles, 16 j-tiles
  size_t i0 = (size_t)ti*128;
  size_t j0 = (size_t)tj*128;
  const short* A  = qe + (size_t)b*NN*DM;
  const short* Bt = ke + (size_t)b*NN*DM;
  int t = threadIdx.x;
  int w = t >> 6, l = t & 63, la = l & 15, lg = l >> 4;
  int wr = w >> 1, wc = w & 1;
  int rs8_0 = ((lg     ) ^ (la&7))*8;
  int rs8_1 = ((lg + 4 ) ^ (la&7))*8;
  f32x4 acc[4][4];
  #pragma unroll
  for (int h=0;h<4;++h)
    #pragma unroll
    for (int c=0;c<4;++c) acc[h][c] = (f32x4){0.f,0.f,0.f,0.f};
  int srow0 = t >> 3;                          // 0..31
  int gch8  = (((t&7) ^ ((t>>3)&7)))*8;        // pre-swizzled global chunk
  const short* Abase = A  + (i0 + srow0)*DM + gch8;
  const short* Bbase = Bt + (j0 + srow0)*DM + gch8;
  for (int k0 = 0; k0 < DM; k0 += 64){
    #pragma unroll
    for (int q = 0; q < 4; ++q){
      gload16(Abase + (size_t)(q*32)*DM + k0, &As[(q*256 + t)*8]);
      gload16(Bbase + (size_t)(q*32)*DM + k0, &Bs[(q*256 + t)*8]);
    }
    __syncthreads();
    #pragma unroll
    for (int s = 0; s < 2; ++s){
      int rs8 = s ? rs8_1 : rs8_0;
      s16x8 af[4], bg[4];
      #pragma unroll
      for (int h=0;h<4;++h) af[h] = *(const s16x8*)&As[(wr*64 + h*16 + la)*64 + rs8];
      #pragma unroll
      for (int c=0;c<4;++c) bg[c] = *(const s16x8*)&Bs[(wc*64 + c*16 + la)*64 + rs8];
      #pragma unroll
      for (int h=0;h<4;++h)
        #pragma unroll
        for (int c=0;c<4;++c)
          acc[h][c] = __builtin_amdgcn_mfma_f32_16x16x32_bf16(af[h], bg[c], acc[h][c], 0, 0, 0);
    }
    __syncthreads();
  }
  const float scale = 0.044194173824159216f;  // 1/sqrt(512)
  float rsum[4][4];
  #pragma unroll
  for (int h=0;h<4;++h)
    #pragma unroll
    for (int r=0;r<4;++r) rsum[h][r] = 0.f;
  // phase 1: exp -> bounce LDS (16 chunks/row, low-3-bit XOR swizzle), accumulate row sums
  #pragma unroll
  for (int h=0;h<4;++h){
    #pragma unroll
    for (int c=0;c<4;++c){
      int colL = wc*64 + c*16 + la;
      int chunk = colL >> 3;
      #pragma unroll
      for (int r=0;r<4;++r){
        int rl = wr*64 + h*16 + lg*4 + r;
        float p = __expf(acc[h][c][r]*scale);
        rsum[h][r] += p;
        S[rl*128 + ((chunk ^ (rl&7))<<3) + (colL&7)] = f2bf(p);
      }
    }
  }
  #pragma unroll
  for (int m = 1; m < 16; m <<= 1){
    #pragma unroll
    for (int h=0;h<4;++h)
      #pragma unroll
      for (int r=0;r<4;++r) rsum[h][r] += __shfl_xor(rsum[h][r], m);
  }
  if (la == 0){
    float* lp = lsum_part + (size_t)(tj*2 + wc)*ROWS + (size_t)b*NN;
    #pragma unroll
    for (int h=0;h<4;++h)
      #pragma unroll
      for (int r=0;r<4;++r)
        lp[i0 + wr*64 + h*16 + lg*4 + r] = rsum[h][r];
  }
  __syncthreads();
  // phase 2: wide coalesced stores (8 x 16B per thread; 128 rows x 16 chunks)
  short* pb = pbuf + (size_t)b*NN*NN;
  #pragma unroll
  for (int q = 0; q < 8; ++q){
    int idx = q*256 + t;          // 0..2047
    int rl = idx >> 4, ch = idx & 15;
    s16x8 vv = *(const s16x8*)&S[rl*128 + ((ch ^ (rl&7))<<3)];
    *(s16x8*)&pb[(size_t)(i0+rl)*NN + j0 + ch*8] = vv;
  }
}

// ---------------- PV GEMM, K=2048, BM=128 x BN=128, 512 threads, BK=64; lsum fused ----------------
__global__ __launch_bounds__(512) void k_pv(const short* __restrict__ pbuf, const short* __restrict__ vt,
        const float* __restrict__ lsum_part, float* __restrict__ attn){
  __shared__ short As[128*64];   // 16 KiB
  __shared__ short Bs[128*64];   // 16 KiB
  __shared__ float linv_lds[128];
  int bid = blockIdx.x;
  int b = bid & 7;
  int r2 = bid >> 3;                 // 0..63
  int ti = r2 & 15, tn = r2 >> 4;    // 16 i-tiles, 4 d-tiles of 128
  size_t i0 = (size_t)ti*128;
  size_t n0 = (size_t)tn*128;
  const short* A  = pbuf + (size_t)b*NN*NN;
  const short* Bt = vt + (size_t)b*DM*NN;
  int t = threadIdx.x;
  int w = t >> 6, l = t & 63, la = l & 15, lg = l >> 4;
  int wr = w >> 1, wc = w & 1;
  int rs8_0 = ((lg     ) ^ (la&7))*8;
  int rs8_1 = ((lg + 4 ) ^ (la&7))*8;
  if (t < 128){
    const float* lp = lsum_part + (size_t)b*NN + i0 + t;
    float s = 0.f;
    #pragma unroll
    for (int i = 0; i < 32; ++i) s += lp[(size_t)i*ROWS];
    linv_lds[t] = 1.0f/s;
  }
  f32x4 acc[2][4];
  #pragma unroll
  for (int h=0;h<2;++h)
    #pragma unroll
    for (int c=0;c<4;++c) acc[h][c] = (f32x4){0.f,0.f,0.f,0.f};
  int srow0 = t >> 3;                          // 0..63
  int gch8  = (((t&7) ^ ((t>>3)&7)))*8;
  const short* Abase = A  + (i0 + srow0)*NN + gch8;
  const short* Bbase = Bt + (n0 + srow0)*NN + gch8;
  for (int k0 = 0; k0 < NN; k0 += 64){
    #pragma unroll
    for (int q = 0; q < 2; ++q){
      gload16(Abase + (size_t)(q*64)*NN + k0, &As[(q*512 + t)*8]);
      gload16(Bbase + (size_t)(q*64)*NN + k0, &Bs[(q*512 + t)*8]);
    }
    __syncthreads();
    #pragma unroll
    for (int s = 0; s < 2; ++s){
      int rs8 = s ? rs8_1 : rs8_0;
      s16x8 af[2], bg[4];
      #pragma unroll
      for (int h=0;h<2;++h) af[h] = *(const s16x8*)&As[(wr*32 + h*16 + la)*64 + rs8];
      #pragma unroll
      for (int c=0;c<4;++c) bg[c] = *(const s16x8*)&Bs[(wc*64 + c*16 + la)*64 + rs8];
      #pragma unroll
      for (int h=0;h<2;++h)
        #pragma unroll
        for (int c=0;c<4;++c)
          acc[h][c] = __builtin_amdgcn_mfma_f32_16x16x32_bf16(af[h], bg[c], acc[h][c], 0, 0, 0);
    }
    __syncthreads();
  }
  #pragma unroll
  for (int h=0;h<2;++h){
    #pragma unroll
    for (int c=0;c<4;++c){
      size_t col = n0 + wc*64 + c*16 + la;
      #pragma unroll
      for (int r=0;r<4;++r){
        int rl = wr*32 + h*16 + lg*4 + r;
        attn[(size_t)b*NN*DM + (i0 + rl)*DM + col] = acc[h][c][r] * linv_lds[rl];
      }
    }
  }
}

// ---------------- res = attn@W2t^T + b2 + feat (MFMA, BM=64), A reg-staged f32->bf16 ----------------
__global__ __launch_bounds__(256) void k_res(const float* __restrict__ attn, const short* __restrict__ W2t,
       const float* __restrict__ b2, const float* __restrict__ feat, float* __restrict__ res){
  __shared__ short As[64*32];
  __shared__ short Bs[64*32];
  int t = threadIdx.x;
  size_t i0 = (size_t)blockIdx.x*64;
  int w = t >> 6, l = t & 63, la = l & 15, lg = l >> 4;
  int rch8 = (lg ^ ((la>>1)&3))*8;
  f32x4 acc[4];
  #pragma unroll
  for (int c=0;c<4;++c) acc[c] = (f32x4){0.f,0.f,0.f,0.f};
  int srow = t >> 2;
  int ch = t & 3;
  int dsw8 = (ch ^ ((srow>>1)&3))*8;          // swizzled LDS chunk for A (matches rch8 read)
  int sk8 = SWZ_SK8(t);
  const float* Arow = attn + (i0 + srow)*DM + ch*8;
  for (int k0 = 0; k0 < DM; k0 += 32){
    f32x4 a0 = *(const f32x4*)&Arow[k0];
    f32x4 a1 = *(const f32x4*)&Arow[k0 + 4];
    s16x8 ab;
    #pragma unroll
    for (int e=0;e<4;++e){ ab[e] = f2bf(a0[e]); ab[4+e] = f2bf(a1[e]); }
    *(s16x8*)&As[srow*32 + dsw8] = ab;
    gload16(W2t + (size_t)srow*DM + k0 + sk8, &Bs[t*8]);
    __syncthreads();
    s16x8 af, bg[4];
    af = *(const s16x8*)&As[(w*16 + la)*32 + rch8];
    #pragma unroll
    for (int c=0;c<4;++c) bg[c] = *(const s16x8*)&Bs[(c*16 + la)*32 + rch8];
    #pragma unroll
    for (int c=0;c<4;++c)
      acc[c] = __builtin_amdgcn_mfma_f32_16x16x32_bf16(af, bg[c], acc[c], 0, 0, 0);
    __syncthreads();
  }
  #pragma unroll
  for (int c=0;c<4;++c){
    int col = c*16 + la;
    #pragma unroll
    for (int r=0;r<4;++r){
      size_t row = i0 + w*16 + lg*4 + r;
      res[row*DP + col] = acc[c][r] + b2[col] + feat[row*DP + col];
    }
  }
}

extern "C" void kernel_launch(void* const* d_in, const int* in_sizes, int n_in,
                              void* d_out, int out_size, void* d_ws, size_t ws_size,
                              hipStream_t stream){
  const float* xyz  = (const float*)d_in[0];
  const float* feat = (const float*)d_in[1];
  const float* W1   = (const float*)d_in[2];
  const float* b1   = (const float*)d_in[3];
  const float* W2   = (const float*)d_in[4];
  const float* b2   = (const float*)d_in[5];
  const float* Wd1  = (const float*)d_in[6];
  const float* bd1  = (const float*)d_in[7];
  const float* Wd2  = (const float*)d_in[8];
  const float* bd2  = (const float*)d_in[9];
  const float* Wq   = (const float*)d_in[10];
  const float* Wk   = (const float*)d_in[11];
  const float* Wv   = (const float*)d_in[12];

  char* ws = (char*)d_ws;                        // max used: 153 MiB
  int*   kidx      = (int*)  (ws + (1ull<<20));  // 1MiB; dead after k_g
  float* kw        = (float*)(ws + (2ull<<20));  // 1MiB; dead after k_g
  float* wsum      = (float*)(ws + (3ull<<20));  // 64KiB; dead after k_g
  float* lsum_part = (float*)(ws + (1ull<<20));  // 2MiB overlay (32 x 16384 f32), after k_g
  short* Wqt   = (short*)(ws + (4ull<<20));      // contiguous: Wqt,Wkt,Wvt,Wd2t (QKV concat rows 0..1535)
  short* Wkt   = Wqt + (size_t)DM*DM;
  short* Wvt   = Wkt + (size_t)DM*DM;
  short* Wd2t  = Wvt + (size_t)DM*DM;
  short* W1t   = (short*)(ws + (6ull<<20));      // 64KiB
  short* W2t   = (short*)(ws + (6ull<<20) + 131072);
  short* featb = (short*)(ws + (7ull<<20));      // 2MiB: 7..9
  short* qe    = (short*)(ws + (9ull<<20));      // 16MiB: 9..25
  short* g     = (short*)(ws + (25ull<<20));     // 16MiB: 25..41; reused as ke
  short* x     = (short*)(ws + (41ull<<20));     // 16MiB: 41..57; reused as vt
  short* wab   = (short*)(ws + (57ull<<20));     // 16MiB: 57..73
  short* ve    = (short*)(ws + (73ull<<20));     // 16MiB: 73..89; dead after k_vt
  short* pbuf  = (short*)(ws + (89ull<<20));     // 64MiB: 89..153 (all 8 batches)
  short* ke = g; short* vt = x;

  float* res  = (float*)d_out;
  float* attn = (float*)d_out + (size_t)ROWS*DP;

  k_knn  <<<ROWS/4, 256, 0, stream>>>(xyz, kidx, kw, wsum);
  k_prep2<<<(4*DM*DM + 2*DM*DP + ROWS*DP)/256, 256, 0, stream>>>(
           Wq, Wk, Wv, Wd2, W1, W2, feat, Wqt, Wkt, Wvt, Wd2t, W1t, W2t, featb);
  k_g    <<<ROWS/4, 256, 0, stream>>>(xyz, Wd1, bd1, kidx, kw, wsum, g);
  k_gemm<DP,0>  <<<dim3(ROWS/128, DM/128), 256, 0, stream>>>(featb, W1t, b1, nullptr, x);
  k_gemm<DM,0>  <<<dim3(ROWS/128, DM/128), 256, 0, stream>>>(g, Wd2t, bd2, nullptr, wab);
  k_gemm3       <<<dim3(ROWS/128, 6), 512, 0, stream>>>(x, Wqt, wab, qe, ke, ve);
  k_vt   <<<dim3(NN/32, DM/32, BB), 256, 0, stream>>>(ve, vt);
  // attention: single pass over all 8 batches (pbuf 64 MiB), BK=64, lsum fused into pv
  k_sexp <<<2048, 256, 0, stream>>>(qe, ke, pbuf, lsum_part);
  k_pv   <<<512, 512, 0, stream>>>(pbuf, vt, lsum_part, attn);
  k_res  <<<ROWS/64, 256, 0, stream>>>(attn, W2t, b2, feat, res);
}

// Round 20
// 246.566 us; speedup vs baseline: 1.0076x; 1.0076x over previous
//
#include <hip/hip_runtime.h>
#include <hip/hip_bf16.h>

#define BB 8
#define NN 2048
#define DP 64
#define DM 512
#define KNNK 16
#define ROWS (BB*NN)   // 16384

// pre-swizzled staging chunk for thread t (pairs with RCH8 read swizzle) -- 32-short rows
#define SWZ_SK8(t) (((((t)&3) ^ (((t)>>3)&3)))*8)

typedef __attribute__((ext_vector_type(8))) short s16x8;
typedef __attribute__((ext_vector_type(4))) short s16x4;
typedef __attribute__((ext_vector_type(4))) float f32x4;

__device__ __forceinline__ float bf2f(short u){
  union { unsigned int i; float f; } v; v.i = ((unsigned int)(unsigned short)u) << 16; return v.f;
}
__device__ __forceinline__ short f2bf(float f){
  __hip_bfloat16 h = __float2bfloat16(f);    // RNE
  return *reinterpret_cast<short*>(&h);
}

// global -> LDS direct (16B per lane)
__device__ __forceinline__ void gload16(const void* g, void* l){
  __builtin_amdgcn_global_load_lds(
      (const __attribute__((address_space(1))) void*)(__UINTPTR_TYPE__)g,
      (__attribute__((address_space(3))) void*)(__UINTPTR_TYPE__)l, 16, 0, 0);
}

// wave-wide min of u32 via DPP (row_shr 1/2/4/8, row_bcast 15/31), broadcast via readlane
__device__ __forceinline__ unsigned wave_min_u32(unsigned v){
  v = min(v, (unsigned)__builtin_amdgcn_update_dpp((int)v, (int)v, 0x111, 0xF, 0xF, false));
  v = min(v, (unsigned)__builtin_amdgcn_update_dpp((int)v, (int)v, 0x112, 0xF, 0xF, false));
  v = min(v, (unsigned)__builtin_amdgcn_update_dpp((int)v, (int)v, 0x114, 0xF, 0xF, false));
  v = min(v, (unsigned)__builtin_amdgcn_update_dpp((int)v, (int)v, 0x118, 0xF, 0xF, false));
  v = min(v, (unsigned)__builtin_amdgcn_update_dpp((int)v, (int)v, 0x142, 0xF, 0xF, false));
  v = min(v, (unsigned)__builtin_amdgcn_update_dpp((int)v, (int)v, 0x143, 0xF, 0xF, false));
  return (unsigned)__builtin_amdgcn_readlane((int)v, 63);
}

// ---------------- exact knn (sq fused): wave-per-row, packed keys, top-3 tournament ----------------
__global__ __launch_bounds__(256) void k_knn(const float* __restrict__ xyz,
        int* __restrict__ kidx, float* __restrict__ kw, float* __restrict__ wsum){
  int row = blockIdx.x*4 + (threadIdx.x >> 6);
  int l = threadIdx.x & 63;
  int b = row >> 11; int i = row & (NN-1);
  const float* xb = xyz + (size_t)b*NN*3;
  float xi0 = xb[3*i], xi1 = xb[3*i+1], xi2 = xb[3*i+2];
  float sqi = xi0*xi0 + xi1*xi1 + xi2*xi2;
  unsigned key[32];
  unsigned m1 = 0xFFFFFFFFu, m2 = 0xFFFFFFFFu, m3 = 0xFFFFFFFFu;
  #pragma unroll
  for (int e = 0; e < 32; ++e){
    int j = e*64 + l;
    float x0 = xb[3*j], x1 = xb[3*j+1], x2 = xb[3*j+2];
    float sqj = x0*x0 + x1*x1 + x2*x2;
    float d = sqi + sqj - 2.0f*(xi0*x0 + xi1*x1 + xi2*x2);
    d = fmaxf(d, 0.f);
    union { float f; unsigned u; } cv; cv.f = d;
    unsigned k = (cv.u & 0xFFFFF800u) | (unsigned)j;
    key[e] = k;
    unsigned r1 = max(k, m1);  m1 = min(k, m1);
    unsigned r2 = max(r1, m2); m2 = min(r1, m2);
    m3 = min(r2, m3);
  }
  float wacc = 0.f;
  for (int sel = 0; sel < KNNK; ++sel){
    unsigned g = wave_min_u32(m1);          // uniform
    unsigned j = g & 2047u;
    union { unsigned u; float f; } dv; dv.u = g & 0xFFFFF800u;
    float wg = 1.0f/(dv.f + 1e-6f);
    wacc += wg;
    if (l == 0){
      kidx[(size_t)row*KNNK + sel] = (int)j;
      kw[(size_t)row*KNNK + sel] = wg;
    }
    bool win = (m1 == g);                   // at most one lane (keys unique)
    if (win){ m1 = m2; m2 = m3; m3 = 0xFFFFFFFFu; }
    if (__any(win && m1 == 0xFFFFFFFFu)){   // rare: winner exhausted its top-3
      if (win && m1 == 0xFFFFFFFFu){
        unsigned mm = 0xFFFFFFFFu;
        #pragma unroll
        for (int e = 0; e < 32; ++e){
          unsigned k2 = key[e];
          mm = min(mm, (k2 > g) ? k2 : 0xFFFFFFFFu);
        }
        m1 = mm;
      }
    }
  }
  if (l == 0) wsum[row] = wacc;
}

// ---------------- one-shot prep: transposed bf16 weights + featb ----------------
__global__ void k_prep2(const float* __restrict__ Wq, const float* __restrict__ Wk,
                        const float* __restrict__ Wv, const float* __restrict__ Wd2,
                        const float* __restrict__ W1, const float* __restrict__ W2,
                        const float* __restrict__ feat,
                        short* __restrict__ Wqt, short* __restrict__ Wkt,
                        short* __restrict__ Wvt, short* __restrict__ Wd2t,
                        short* __restrict__ W1t, short* __restrict__ W2t,
                        short* __restrict__ featb){
  int idx = blockIdx.x*256 + threadIdx.x;
  if (idx < 4*DM*DM){
    int m = idx >> 18;
    int r = idx & (DM*DM-1);
    int n = r >> 9, k = r & 511;
    const float* W = (m==0)?Wq:(m==1)?Wk:(m==2)?Wv:Wd2;
    short* Wt = (m==0)?Wqt:(m==1)?Wkt:(m==2)?Wvt:Wd2t;
    Wt[r] = f2bf(W[k*DM + n]);
  } else if (idx < 4*DM*DM + DM*DP){
    int r = idx - 4*DM*DM;
    int n = r >> 6, k = r & 63;
    W1t[r] = f2bf(W1[(size_t)k*DM + n]);
  } else if (idx < 4*DM*DM + 2*DM*DP){
    int r = idx - 4*DM*DM - DM*DP;
    int n = r >> 9, k = r & 511;
    W2t[r] = f2bf(W2[(size_t)k*DP + n]);
  } else {
    int r = idx - 4*DM*DM - 2*DM*DP;
    featb[r] = f2bf(feat[r]);
  }
}

// ---------------- g = (sum_j w_j * relu(xyz[idx_j]@Wd1 + bd1)) / wsum, fused, bf16 ----------------
__global__ __launch_bounds__(256) void k_g(const float* __restrict__ xyz, const float* __restrict__ Wd1,
                   const float* __restrict__ bd1, const int* __restrict__ kidx,
                   const float* __restrict__ kw, const float* __restrict__ wsum, short* __restrict__ g){
  int bid = blockIdx.x;
  int p = ((bid&7)<<11) + ((bid>>3)<<2) + (threadIdx.x>>6);   // batch = bid&7 (XCD-pinned)
  int c8 = (threadIdx.x&63)*8;
  int b = p >> 11;
  const float* xbase = xyz + (size_t)b*NN*3;
  float wd0[8], wd1v[8], wd2v[8], bb[8];
  #pragma unroll
  for (int e=0;e<8;++e){
    wd0[e]  = Wd1[c8+e];
    wd1v[e] = Wd1[DM + c8+e];
    wd2v[e] = Wd1[2*DM + c8+e];
    bb[e]   = bd1[c8+e];
  }
  int jj[KNNK]; float wj[KNNK];
  #pragma unroll
  for (int j = 0; j < KNNK; ++j){
    jj[j] = kidx[(size_t)p*KNNK + j];
    wj[j] = kw[(size_t)p*KNNK + j];
  }
  float acc[8] = {0,0,0,0,0,0,0,0};
  #pragma unroll
  for (int j = 0; j < KNNK; ++j){
    float x0 = xbase[3*jj[j]], x1 = xbase[3*jj[j]+1], x2 = xbase[3*jj[j]+2];
    float w = wj[j];
    #pragma unroll
    for (int e=0;e<8;++e){
      float v = fmaf(x0, wd0[e], fmaf(x1, wd1v[e], fmaf(x2, wd2v[e], bb[e])));
      acc[e] = fmaf(w, fmaxf(v, 0.f), acc[e]);
    }
  }
  float inv = 1.0f/wsum[p];
  s16x8 o;
  #pragma unroll
  for (int e=0;e<8;++e) o[e] = f2bf(acc[e]*inv);
  *(s16x8*)&g[(size_t)p*DM + c8] = o;
}

// ---------------- bf16 MFMA GEMM (BM=128,BN=128), XOR-swizzled LDS (BK=32) ----------------
template<int KD, int MODE>
__global__ __launch_bounds__(256) void k_gemm(const short* __restrict__ A, const short* __restrict__ Bt,
       const float* __restrict__ bias, const short* __restrict__ addb, short* __restrict__ outb){
  __shared__ short As[128*32];
  __shared__ short Bs[128*32];
  int t = threadIdx.x;
  size_t i0 = (size_t)blockIdx.x*128, n0 = (size_t)blockIdx.y*128;
  int w = t >> 6, l = t & 63, la = l & 15, lg = l >> 4;
  int wr = w >> 1, wc = w & 1;
  int rch8 = (lg ^ ((la>>1)&3))*8;
  f32x4 acc[4][4];
  #pragma unroll
  for (int h=0;h<4;++h)
    #pragma unroll
    for (int c=0;c<4;++c) acc[h][c] = (f32x4){0.f,0.f,0.f,0.f};
  int srow = t >> 2; int sk8 = SWZ_SK8(t);
  const short* Ab  = A  + (i0 + srow)*KD + sk8;
  const short* Ab2 = A  + (i0 + 64 + srow)*KD + sk8;
  const short* Bb  = Bt + (n0 + srow)*KD + sk8;
  const short* Bb2 = Bt + (n0 + 64 + srow)*KD + sk8;
  short* Asd  = &As[t*8];      short* Asd2 = &As[2048 + t*8];
  short* Bsd  = &Bs[t*8];      short* Bsd2 = &Bs[2048 + t*8];
  for (int k0 = 0; k0 < KD; k0 += 32){
    gload16(Ab  + k0, Asd);
    gload16(Ab2 + k0, Asd2);
    gload16(Bb  + k0, Bsd);
    gload16(Bb2 + k0, Bsd2);
    __syncthreads();
    s16x8 af[4], bg[4];
    #pragma unroll
    for (int h=0;h<4;++h) af[h] = *(const s16x8*)&As[(wr*64 + h*16 + la)*32 + rch8];
    #pragma unroll
    for (int c=0;c<4;++c) bg[c] = *(const s16x8*)&Bs[(wc*64 + c*16 + la)*32 + rch8];
    #pragma unroll
    for (int h=0;h<4;++h)
      #pragma unroll
      for (int c=0;c<4;++c)
        acc[h][c] = __builtin_amdgcn_mfma_f32_16x16x32_bf16(af[h], bg[c], acc[h][c], 0, 0, 0);
    __syncthreads();
  }
  #pragma unroll
  for (int h=0;h<4;++h){
    #pragma unroll
    for (int c=0;c<4;++c){
      size_t col = n0 + wc*64 + c*16 + la;
      #pragma unroll
      for (int r=0;r<4;++r){
        size_t row = i0 + wr*64 + h*16 + lg*4 + r;
        float v = acc[h][c][r];
        if (MODE == 0) outb[row*DM + col] = f2bf(v + bias[col]);
        else           outb[row*DM + col] = f2bf(v + bf2f(addb[row*DM + col]));
      }
    }
  }
}

// ---------------- merged QKV GEMM, 512 threads, BM=128 x BN=256 ----------------
__global__ __launch_bounds__(512) void k_gemm3(const short* __restrict__ A, const short* __restrict__ Bt,
       const short* __restrict__ addb, short* __restrict__ q, short* __restrict__ k, short* __restrict__ v){
  __shared__ short As[128*32];   // 8 KiB
  __shared__ short Bs[256*32];   // 16 KiB
  int t = threadIdx.x;
  int by = blockIdx.y;
  short* outb = (by < 2) ? q : (by < 4) ? k : v;
  size_t i0 = (size_t)blockIdx.x*128;
  size_t n0 = (size_t)by*256;          // row into 1536-row concat
  size_t c0 = (size_t)(by & 1)*256;    // output col base
  int w = t >> 6, l = t & 63, la = l & 15, lg = l >> 4;
  int wr = w >> 2, wc = w & 3;         // 2 x 4 waves: 64 rows x 64 cols each
  int rch8 = (lg ^ ((la>>1)&3))*8;
  f32x4 acc[4][4];
  #pragma unroll
  for (int h=0;h<4;++h)
    #pragma unroll
    for (int c=0;c<4;++c) acc[h][c] = (f32x4){0.f,0.f,0.f,0.f};
  int srow = t >> 2; int sk8 = SWZ_SK8(t);    // srow 0..127
  const short* Ab  = A  + (i0 + srow)*DM + sk8;
  const short* Bb  = Bt + (n0 + srow)*DM + sk8;
  const short* Bb2 = Bt + (n0 + 128 + srow)*DM + sk8;
  short* Asd = &As[t*8];
  short* Bsd = &Bs[t*8];  short* Bsd2 = &Bs[4096 + t*8];
  for (int k0 = 0; k0 < DM; k0 += 32){
    gload16(Ab  + k0, Asd);
    gload16(Bb  + k0, Bsd);
    gload16(Bb2 + k0, Bsd2);
    __syncthreads();
    s16x8 af[4], bg[4];
    #pragma unroll
    for (int h=0;h<4;++h) af[h] = *(const s16x8*)&As[(wr*64 + h*16 + la)*32 + rch8];
    #pragma unroll
    for (int c=0;c<4;++c) bg[c] = *(const s16x8*)&Bs[(wc*64 + c*16 + la)*32 + rch8];
    #pragma unroll
    for (int h=0;h<4;++h)
      #pragma unroll
      for (int c=0;c<4;++c)
        acc[h][c] = __builtin_amdgcn_mfma_f32_16x16x32_bf16(af[h], bg[c], acc[h][c], 0, 0, 0);
    __syncthreads();
  }
  #pragma unroll
  for (int h=0;h<4;++h){
    #pragma unroll
    for (int c=0;c<4;++c){
      size_t col = c0 + wc*64 + c*16 + la;
      #pragma unroll
      for (int r=0;r<4;++r){
        size_t row = i0 + wr*64 + h*16 + lg*4 + r;
        outb[row*DM + col] = f2bf(acc[h][c][r] + bf2f(addb[row*DM + col]));
      }
    }
  }
}

// ---------------- transpose ve -> vt[b][d][j] ----------------
__global__ __launch_bounds__(256) void k_vt(const short* __restrict__ ve, short* __restrict__ vt){
  int j0 = blockIdx.x*32, d0 = blockIdx.y*32, b = blockIdx.z;
  __shared__ short tile[32][36];
  int t = threadIdx.x;
  int r = t >> 3, c4 = (t & 7)*4;
  const short* vb = ve + (size_t)b*NN*DM;
  *(s16x4*)&tile[r][c4] = *(const s16x4*)&vb[(size_t)(j0+r)*DM + d0 + c4];
  __syncthreads();
  s16x4 o;
  #pragma unroll
  for (int e=0;e<4;++e) o[e] = tile[c4+e][r];
  short* ob = vt + (size_t)b*DM*NN;
  *(s16x4*)&ob[(size_t)(d0+r)*NN + j0 + c4] = o;
}

// ---------------- S-GEMM + exp, BK=64, direct stores (R17 epilogue) ----------------
__global__ __launch_bounds__(256) void k_sexp(const short* __restrict__ qe, const short* __restrict__ ke,
       short* __restrict__ pbuf, float* __restrict__ lsum_part){
  __shared__ short As[128*64];   // 16 KiB
  __shared__ short Bs[128*64];   // 16 KiB
  int bid = blockIdx.x;
  int b = bid & 7;
  int r2 = bid >> 3;                 // 0..255
  int ti = r2 & 15, tj = r2 >> 4;    // 16 i-tiles, 16 j-tiles
  size_t i0 = (size_t)ti*128;
  size_t j0 = (size_t)tj*128;
  const short* A  = qe + (size_t)b*NN*DM;
  const short* Bt = ke + (size_t)b*NN*DM;
  int t = threadIdx.x;
  int w = t >> 6, l = t & 63, la = l & 15, lg = l >> 4;
  int wr = w >> 1, wc = w & 1;
  int rs8_0 = ((lg     ) ^ (la&7))*8;
  int rs8_1 = ((lg + 4 ) ^ (la&7))*8;
  f32x4 acc[4][4];
  #pragma unroll
  for (int h=0;h<4;++h)
    #pragma unroll
    for (int c=0;c<4;++c) acc[h][c] = (f32x4){0.f,0.f,0.f,0.f};
  int srow0 = t >> 3;                          // 0..31
  int gch8  = (((t&7) ^ ((t>>3)&7)))*8;        // pre-swizzled global chunk
  const short* Abase = A  + (i0 + srow0)*DM + gch8;
  const short* Bbase = Bt + (j0 + srow0)*DM + gch8;
  for (int k0 = 0; k0 < DM; k0 += 64){
    #pragma unroll
    for (int q = 0; q < 4; ++q){
      gload16(Abase + (size_t)(q*32)*DM + k0, &As[(q*256 + t)*8]);
      gload16(Bbase + (size_t)(q*32)*DM + k0, &Bs[(q*256 + t)*8]);
    }
    __syncthreads();
    #pragma unroll
    for (int s = 0; s < 2; ++s){
      int rs8 = s ? rs8_1 : rs8_0;
      s16x8 af[4], bg[4];
      #pragma unroll
      for (int h=0;h<4;++h) af[h] = *(const s16x8*)&As[(wr*64 + h*16 + la)*64 + rs8];
      #pragma unroll
      for (int c=0;c<4;++c) bg[c] = *(const s16x8*)&Bs[(wc*64 + c*16 + la)*64 + rs8];
      #pragma unroll
      for (int h=0;h<4;++h)
        #pragma unroll
        for (int c=0;c<4;++c)
          acc[h][c] = __builtin_amdgcn_mfma_f32_16x16x32_bf16(af[h], bg[c], acc[h][c], 0, 0, 0);
    }
    __syncthreads();
  }
  const float scale = 0.044194173824159216f;  // 1/sqrt(512)
  short* pb = pbuf + (size_t)b*NN*NN;
  float rsum[4][4];
  #pragma unroll
  for (int h=0;h<4;++h)
    #pragma unroll
    for (int r=0;r<4;++r) rsum[h][r] = 0.f;
  #pragma unroll
  for (int h=0;h<4;++h){
    #pragma unroll
    for (int c=0;c<4;++c){
      size_t col = j0 + wc*64 + c*16 + la;
      #pragma unroll
      for (int r=0;r<4;++r){
        size_t row = i0 + wr*64 + h*16 + lg*4 + r;
        float p = __expf(acc[h][c][r]*scale);
        rsum[h][r] += p;
        pb[row*NN + col] = f2bf(p);
      }
    }
  }
  #pragma unroll
  for (int m = 1; m < 16; m <<= 1){
    #pragma unroll
    for (int h=0;h<4;++h)
      #pragma unroll
      for (int r=0;r<4;++r) rsum[h][r] += __shfl_xor(rsum[h][r], m);
  }
  if (la == 0){
    float* lp = lsum_part + (size_t)(tj*2 + wc)*ROWS + (size_t)b*NN;
    #pragma unroll
    for (int h=0;h<4;++h)
      #pragma unroll
      for (int r=0;r<4;++r)
        lp[i0 + wr*64 + h*16 + lg*4 + r] = rsum[h][r];
  }
}

// ---------------- PV GEMM, K=2048, BM=128 x BN=128, 512 threads, BK=64; lsum fused ----------------
__global__ __launch_bounds__(512) void k_pv(const short* __restrict__ pbuf, const short* __restrict__ vt,
        const float* __restrict__ lsum_part, float* __restrict__ attn){
  __shared__ short As[128*64];   // 16 KiB
  __shared__ short Bs[128*64];   // 16 KiB
  __shared__ float linv_lds[128];
  int bid = blockIdx.x;
  int b = bid & 7;
  int r2 = bid >> 3;                 // 0..63
  int ti = r2 & 15, tn = r2 >> 4;    // 16 i-tiles, 4 d-tiles of 128
  size_t i0 = (size_t)ti*128;
  size_t n0 = (size_t)tn*128;
  const short* A  = pbuf + (size_t)b*NN*NN;
  const short* Bt = vt + (size_t)b*DM*NN;
  int t = threadIdx.x;
  int w = t >> 6, l = t & 63, la = l & 15, lg = l >> 4;
  int wr = w >> 1, wc = w & 1;
  int rs8_0 = ((lg     ) ^ (la&7))*8;
  int rs8_1 = ((lg + 4 ) ^ (la&7))*8;
  if (t < 128){
    const float* lp = lsum_part + (size_t)b*NN + i0 + t;
    float s = 0.f;
    #pragma unroll
    for (int i = 0; i < 32; ++i) s += lp[(size_t)i*ROWS];
    linv_lds[t] = 1.0f/s;
  }
  f32x4 acc[2][4];
  #pragma unroll
  for (int h=0;h<2;++h)
    #pragma unroll
    for (int c=0;c<4;++c) acc[h][c] = (f32x4){0.f,0.f,0.f,0.f};
  int srow0 = t >> 3;                          // 0..63
  int gch8  = (((t&7) ^ ((t>>3)&7)))*8;
  const short* Abase = A  + (i0 + srow0)*NN + gch8;
  const short* Bbase = Bt + (n0 + srow0)*NN + gch8;
  for (int k0 = 0; k0 < NN; k0 += 64){
    #pragma unroll
    for (int q = 0; q < 2; ++q){
      gload16(Abase + (size_t)(q*64)*NN + k0, &As[(q*512 + t)*8]);
      gload16(Bbase + (size_t)(q*64)*NN + k0, &Bs[(q*512 + t)*8]);
    }
    __syncthreads();
    #pragma unroll
    for (int s = 0; s < 2; ++s){
      int rs8 = s ? rs8_1 : rs8_0;
      s16x8 af[2], bg[4];
      #pragma unroll
      for (int h=0;h<2;++h) af[h] = *(const s16x8*)&As[(wr*32 + h*16 + la)*64 + rs8];
      #pragma unroll
      for (int c=0;c<4;++c) bg[c] = *(const s16x8*)&Bs[(wc*64 + c*16 + la)*64 + rs8];
      #pragma unroll
      for (int h=0;h<2;++h)
        #pragma unroll
        for (int c=0;c<4;++c)
          acc[h][c] = __builtin_amdgcn_mfma_f32_16x16x32_bf16(af[h], bg[c], acc[h][c], 0, 0, 0);
    }
    __syncthreads();
  }
  #pragma unroll
  for (int h=0;h<2;++h){
    #pragma unroll
    for (int c=0;c<4;++c){
      size_t col = n0 + wc*64 + c*16 + la;
      #pragma unroll
      for (int r=0;r<4;++r){
        int rl = wr*32 + h*16 + lg*4 + r;
        attn[(size_t)b*NN*DM + (i0 + rl)*DM + col] = acc[h][c][r] * linv_lds[rl];
      }
    }
  }
}

// ---------------- res = attn@W2t^T + b2 + feat (MFMA, BM=64), A reg-staged f32->bf16 ----------------
__global__ __launch_bounds__(256) void k_res(const float* __restrict__ attn, const short* __restrict__ W2t,
       const float* __restrict__ b2, const float* __restrict__ feat, float* __restrict__ res){
  __shared__ short As[64*32];
  __shared__ short Bs[64*32];
  int t = threadIdx.x;
  size_t i0 = (size_t)blockIdx.x*64;
  int w = t >> 6, l = t & 63, la = l & 15, lg = l >> 4;
  int rch8 = (lg ^ ((la>>1)&3))*8;
  f32x4 acc[4];
  #pragma unroll
  for (int c=0;c<4;++c) acc[c] = (f32x4){0.f,0.f,0.f,0.f};
  int srow = t >> 2;
  int ch = t & 3;
  int dsw8 = (ch ^ ((srow>>1)&3))*8;          // swizzled LDS chunk for A (matches rch8 read)
  int sk8 = SWZ_SK8(t);
  const float* Arow = attn + (i0 + srow)*DM + ch*8;
  for (int k0 = 0; k0 < DM; k0 += 32){
    f32x4 a0 = *(const f32x4*)&Arow[k0];
    f32x4 a1 = *(const f32x4*)&Arow[k0 + 4];
    s16x8 ab;
    #pragma unroll
    for (int e=0;e<4;++e){ ab[e] = f2bf(a0[e]); ab[4+e] = f2bf(a1[e]); }
    *(s16x8*)&As[srow*32 + dsw8] = ab;
    gload16(W2t + (size_t)srow*DM + k0 + sk8, &Bs[t*8]);
    __syncthreads();
    s16x8 af, bg[4];
    af = *(const s16x8*)&As[(w*16 + la)*32 + rch8];
    #pragma unroll
    for (int c=0;c<4;++c) bg[c] = *(const s16x8*)&Bs[(c*16 + la)*32 + rch8];
    #pragma unroll
    for (int c=0;c<4;++c)
      acc[c] = __builtin_amdgcn_mfma_f32_16x16x32_bf16(af, bg[c], acc[c], 0, 0, 0);
    __syncthreads();
  }
  #pragma unroll
  for (int c=0;c<4;++c){
    int col = c*16 + la;
    #pragma unroll
    for (int r=0;r<4;++r){
      size_t row = i0 + w*16 + lg*4 + r;
      res[row*DP + col] = acc[c][r] + b2[col] + feat[row*DP + col];
    }
  }
}

extern "C" void kernel_launch(void* const* d_in, const int* in_sizes, int n_in,
                              void* d_out, int out_size, void* d_ws, size_t ws_size,
                              hipStream_t stream){
  const float* xyz  = (const float*)d_in[0];
  const float* feat = (const float*)d_in[1];
  const float* W1   = (const float*)d_in[2];
  const float* b1   = (const float*)d_in[3];
  const float* W2   = (const float*)d_in[4];
  const float* b2   = (const float*)d_in[5];
  const float* Wd1  = (const float*)d_in[6];
  const float* bd1  = (const float*)d_in[7];
  const float* Wd2  = (const float*)d_in[8];
  const float* bd2  = (const float*)d_in[9];
  const float* Wq   = (const float*)d_in[10];
  const float* Wk   = (const float*)d_in[11];
  const float* Wv   = (const float*)d_in[12];

  char* ws = (char*)d_ws;                        // max used: 153 MiB
  int*   kidx      = (int*)  (ws + (1ull<<20));  // 1MiB; dead after k_g
  float* kw        = (float*)(ws + (2ull<<20));  // 1MiB; dead after k_g
  float* wsum      = (float*)(ws + (3ull<<20));  // 64KiB; dead after k_g
  float* lsum_part = (float*)(ws + (1ull<<20));  // 2MiB overlay (32 x 16384 f32), after k_g
  short* Wqt   = (short*)(ws + (4ull<<20));      // contiguous: Wqt,Wkt,Wvt,Wd2t (QKV concat rows 0..1535)
  short* Wkt   = Wqt + (size_t)DM*DM;
  short* Wvt   = Wkt + (size_t)DM*DM;
  short* Wd2t  = Wvt + (size_t)DM*DM;
  short* W1t   = (short*)(ws + (6ull<<20));      // 64KiB
  short* W2t   = (short*)(ws + (6ull<<20) + 131072);
  short* featb = (short*)(ws + (7ull<<20));      // 2MiB: 7..9
  short* qe    = (short*)(ws + (9ull<<20));      // 16MiB: 9..25
  short* g     = (short*)(ws + (25ull<<20));     // 16MiB: 25..41; reused as ke
  short* x     = (short*)(ws + (41ull<<20));     // 16MiB: 41..57; reused as vt
  short* wab   = (short*)(ws + (57ull<<20));     // 16MiB: 57..73
  short* ve    = (short*)(ws + (73ull<<20));     // 16MiB: 73..89; dead after k_vt
  short* pbuf  = (short*)(ws + (89ull<<20));     // 64MiB: 89..153 (all 8 batches)
  short* ke = g; short* vt = x;

  float* res  = (float*)d_out;
  float* attn = (float*)d_out + (size_t)ROWS*DP;

  k_knn  <<<ROWS/4, 256, 0, stream>>>(xyz, kidx, kw, wsum);
  k_prep2<<<(4*DM*DM + 2*DM*DP + ROWS*DP)/256, 256, 0, stream>>>(
           Wq, Wk, Wv, Wd2, W1, W2, feat, Wqt, Wkt, Wvt, Wd2t, W1t, W2t, featb);
  k_g    <<<ROWS/4, 256, 0, stream>>>(xyz, Wd1, bd1, kidx, kw, wsum, g);
  k_gemm<DP,0>  <<<dim3(ROWS/128, DM/128), 256, 0, stream>>>(featb, W1t, b1, nullptr, x);
  k_gemm<DM,0>  <<<dim3(ROWS/128, DM/128), 256, 0, stream>>>(g, Wd2t, bd2, nullptr, wab);
  k_gemm3       <<<dim3(ROWS/128, 6), 512, 0, stream>>>(x, Wqt, wab, qe, ke, ve);
  k_vt   <<<dim3(NN/32, DM/32, BB), 256, 0, stream>>>(ve, vt);
  // attention: single pass over all 8 batches (pbuf 64 MiB), BK=64, lsum fused into pv
  k_sexp <<<2048, 256, 0, stream>>>(qe, ke, pbuf, lsum_part);
  k_pv   <<<512, 512, 0, stream>>>(pbuf, vt, lsum_part, attn);
  k_res  <<<ROWS/64, 256, 0, stream>>>(attn, W2t, b2, feat, res);
}

// Round 21
// 238.040 us; speedup vs baseline: 1.0437x; 1.0358x over previous
//
#include <hip/hip_runtime.h>
#include <hip/hip_bf16.h>

#define BB 8
#define NN 2048
#define DP 64
#define DM 512
#define KNNK 16
#define ROWS (BB*NN)   // 16384

// pre-swizzled staging chunk for thread t (pairs with RCH8 read swizzle) -- 32-short rows
#define SWZ_SK8(t) (((((t)&3) ^ (((t)>>3)&3)))*8)

typedef __attribute__((ext_vector_type(8))) short s16x8;
typedef __attribute__((ext_vector_type(4))) short s16x4;
typedef __attribute__((ext_vector_type(4))) float f32x4;

__device__ __forceinline__ float bf2f(short u){
  union { unsigned int i; float f; } v; v.i = ((unsigned int)(unsigned short)u) << 16; return v.f;
}
__device__ __forceinline__ short f2bf(float f){
  __hip_bfloat16 h = __float2bfloat16(f);    // RNE
  return *reinterpret_cast<short*>(&h);
}

// global -> LDS direct (16B per lane)
__device__ __forceinline__ void gload16(const void* g, void* l){
  __builtin_amdgcn_global_load_lds(
      (const __attribute__((address_space(1))) void*)(__UINTPTR_TYPE__)g,
      (__attribute__((address_space(3))) void*)(__UINTPTR_TYPE__)l, 16, 0, 0);
}

// wave-wide min of u32 via DPP (row_shr 1/2/4/8, row_bcast 15/31), broadcast via readlane
__device__ __forceinline__ unsigned wave_min_u32(unsigned v){
  v = min(v, (unsigned)__builtin_amdgcn_update_dpp((int)v, (int)v, 0x111, 0xF, 0xF, false));
  v = min(v, (unsigned)__builtin_amdgcn_update_dpp((int)v, (int)v, 0x112, 0xF, 0xF, false));
  v = min(v, (unsigned)__builtin_amdgcn_update_dpp((int)v, (int)v, 0x114, 0xF, 0xF, false));
  v = min(v, (unsigned)__builtin_amdgcn_update_dpp((int)v, (int)v, 0x118, 0xF, 0xF, false));
  v = min(v, (unsigned)__builtin_amdgcn_update_dpp((int)v, (int)v, 0x142, 0xF, 0xF, false));
  v = min(v, (unsigned)__builtin_amdgcn_update_dpp((int)v, (int)v, 0x143, 0xF, 0xF, false));
  return (unsigned)__builtin_amdgcn_readlane((int)v, 63);
}

// ---------------- exact knn (sq fused): wave-per-row, packed keys, top-3 tournament ----------------
__global__ __launch_bounds__(256) void k_knn(const float* __restrict__ xyz,
        int* __restrict__ kidx, float* __restrict__ kw, float* __restrict__ wsum){
  int row = blockIdx.x*4 + (threadIdx.x >> 6);
  int l = threadIdx.x & 63;
  int b = row >> 11; int i = row & (NN-1);
  const float* xb = xyz + (size_t)b*NN*3;
  float xi0 = xb[3*i], xi1 = xb[3*i+1], xi2 = xb[3*i+2];
  float sqi = xi0*xi0 + xi1*xi1 + xi2*xi2;
  unsigned key[32];
  unsigned m1 = 0xFFFFFFFFu, m2 = 0xFFFFFFFFu, m3 = 0xFFFFFFFFu;
  #pragma unroll
  for (int e = 0; e < 32; ++e){
    int j = e*64 + l;
    float x0 = xb[3*j], x1 = xb[3*j+1], x2 = xb[3*j+2];
    float sqj = x0*x0 + x1*x1 + x2*x2;
    float d = sqi + sqj - 2.0f*(xi0*x0 + xi1*x1 + xi2*x2);
    d = fmaxf(d, 0.f);
    union { float f; unsigned u; } cv; cv.f = d;
    unsigned k = (cv.u & 0xFFFFF800u) | (unsigned)j;
    key[e] = k;
    unsigned r1 = max(k, m1);  m1 = min(k, m1);
    unsigned r2 = max(r1, m2); m2 = min(r1, m2);
    m3 = min(r2, m3);
  }
  float wacc = 0.f;
  for (int sel = 0; sel < KNNK; ++sel){
    unsigned g = wave_min_u32(m1);          // uniform
    unsigned j = g & 2047u;
    union { unsigned u; float f; } dv; dv.u = g & 0xFFFFF800u;
    float wg = 1.0f/(dv.f + 1e-6f);
    wacc += wg;
    if (l == 0){
      kidx[(size_t)row*KNNK + sel] = (int)j;
      kw[(size_t)row*KNNK + sel] = wg;
    }
    bool win = (m1 == g);                   // at most one lane (keys unique)
    if (win){ m1 = m2; m2 = m3; m3 = 0xFFFFFFFFu; }
    if (__any(win && m1 == 0xFFFFFFFFu)){   // rare: winner exhausted its top-3
      if (win && m1 == 0xFFFFFFFFu){
        unsigned mm = 0xFFFFFFFFu;
        #pragma unroll
        for (int e = 0; e < 32; ++e){
          unsigned k2 = key[e];
          mm = min(mm, (k2 > g) ? k2 : 0xFFFFFFFFu);
        }
        m1 = mm;
      }
    }
  }
  if (l == 0) wsum[row] = wacc;
}

// ---------------- one-shot prep: transposed bf16 weights + featb ----------------
__global__ void k_prep2(const float* __restrict__ Wq, const float* __restrict__ Wk,
                        const float* __restrict__ Wv, const float* __restrict__ Wd2,
                        const float* __restrict__ W1, const float* __restrict__ W2,
                        const float* __restrict__ feat,
                        short* __restrict__ Wqt, short* __restrict__ Wkt,
                        short* __restrict__ Wvt, short* __restrict__ Wd2t,
                        short* __restrict__ W1t, short* __restrict__ W2t,
                        short* __restrict__ featb){
  int idx = blockIdx.x*256 + threadIdx.x;
  if (idx < 4*DM*DM){
    int m = idx >> 18;
    int r = idx & (DM*DM-1);
    int n = r >> 9, k = r & 511;
    const float* W = (m==0)?Wq:(m==1)?Wk:(m==2)?Wv:Wd2;
    short* Wt = (m==0)?Wqt:(m==1)?Wkt:(m==2)?Wvt:Wd2t;
    Wt[r] = f2bf(W[k*DM + n]);
  } else if (idx < 4*DM*DM + DM*DP){
    int r = idx - 4*DM*DM;
    int n = r >> 6, k = r & 63;
    W1t[r] = f2bf(W1[(size_t)k*DM + n]);
  } else if (idx < 4*DM*DM + 2*DM*DP){
    int r = idx - 4*DM*DM - DM*DP;
    int n = r >> 9, k = r & 511;
    W2t[r] = f2bf(W2[(size_t)k*DP + n]);
  } else {
    int r = idx - 4*DM*DM - 2*DM*DP;
    featb[r] = f2bf(feat[r]);
  }
}

// ---------------- g = (sum_j w_j * relu(xyz[idx_j]@Wd1 + bd1)) / wsum, fused, bf16 ----------------
__global__ __launch_bounds__(256) void k_g(const float* __restrict__ xyz, const float* __restrict__ Wd1,
                   const float* __restrict__ bd1, const int* __restrict__ kidx,
                   const float* __restrict__ kw, const float* __restrict__ wsum, short* __restrict__ g){
  int bid = blockIdx.x;
  int p = ((bid&7)<<11) + ((bid>>3)<<2) + (threadIdx.x>>6);   // batch = bid&7 (XCD-pinned)
  int c8 = (threadIdx.x&63)*8;
  int b = p >> 11;
  const float* xbase = xyz + (size_t)b*NN*3;
  float wd0[8], wd1v[8], wd2v[8], bb[8];
  #pragma unroll
  for (int e=0;e<8;++e){
    wd0[e]  = Wd1[c8+e];
    wd1v[e] = Wd1[DM + c8+e];
    wd2v[e] = Wd1[2*DM + c8+e];
    bb[e]   = bd1[c8+e];
  }
  int jj[KNNK]; float wj[KNNK];
  #pragma unroll
  for (int j = 0; j < KNNK; ++j){
    jj[j] = kidx[(size_t)p*KNNK + j];
    wj[j] = kw[(size_t)p*KNNK + j];
  }
  float acc[8] = {0,0,0,0,0,0,0,0};
  #pragma unroll
  for (int j = 0; j < KNNK; ++j){
    float x0 = xbase[3*jj[j]], x1 = xbase[3*jj[j]+1], x2 = xbase[3*jj[j]+2];
    float w = wj[j];
    #pragma unroll
    for (int e=0;e<8;++e){
      float v = fmaf(x0, wd0[e], fmaf(x1, wd1v[e], fmaf(x2, wd2v[e], bb[e])));
      acc[e] = fmaf(w, fmaxf(v, 0.f), acc[e]);
    }
  }
  float inv = 1.0f/wsum[p];
  s16x8 o;
  #pragma unroll
  for (int e=0;e<8;++e) o[e] = f2bf(acc[e]*inv);
  *(s16x8*)&g[(size_t)p*DM + c8] = o;
}

// ---------------- bf16 MFMA GEMM (BM=128,BN=128), XOR-swizzled LDS (BK=32) ----------------
template<int KD, int MODE>
__global__ __launch_bounds__(256) void k_gemm(const short* __restrict__ A, const short* __restrict__ Bt,
       const float* __restrict__ bias, const short* __restrict__ addb, short* __restrict__ outb){
  __shared__ short As[128*32];
  __shared__ short Bs[128*32];
  int t = threadIdx.x;
  size_t i0 = (size_t)blockIdx.x*128, n0 = (size_t)blockIdx.y*128;
  int w = t >> 6, l = t & 63, la = l & 15, lg = l >> 4;
  int wr = w >> 1, wc = w & 1;
  int rch8 = (lg ^ ((la>>1)&3))*8;
  f32x4 acc[4][4];
  #pragma unroll
  for (int h=0;h<4;++h)
    #pragma unroll
    for (int c=0;c<4;++c) acc[h][c] = (f32x4){0.f,0.f,0.f,0.f};
  int srow = t >> 2; int sk8 = SWZ_SK8(t);
  const short* Ab  = A  + (i0 + srow)*KD + sk8;
  const short* Ab2 = A  + (i0 + 64 + srow)*KD + sk8;
  const short* Bb  = Bt + (n0 + srow)*KD + sk8;
  const short* Bb2 = Bt + (n0 + 64 + srow)*KD + sk8;
  short* Asd  = &As[t*8];      short* Asd2 = &As[2048 + t*8];
  short* Bsd  = &Bs[t*8];      short* Bsd2 = &Bs[2048 + t*8];
  for (int k0 = 0; k0 < KD; k0 += 32){
    gload16(Ab  + k0, Asd);
    gload16(Ab2 + k0, Asd2);
    gload16(Bb  + k0, Bsd);
    gload16(Bb2 + k0, Bsd2);
    __syncthreads();
    s16x8 af[4], bg[4];
    #pragma unroll
    for (int h=0;h<4;++h) af[h] = *(const s16x8*)&As[(wr*64 + h*16 + la)*32 + rch8];
    #pragma unroll
    for (int c=0;c<4;++c) bg[c] = *(const s16x8*)&Bs[(wc*64 + c*16 + la)*32 + rch8];
    #pragma unroll
    for (int h=0;h<4;++h)
      #pragma unroll
      for (int c=0;c<4;++c)
        acc[h][c] = __builtin_amdgcn_mfma_f32_16x16x32_bf16(af[h], bg[c], acc[h][c], 0, 0, 0);
    __syncthreads();
  }
  #pragma unroll
  for (int h=0;h<4;++h){
    #pragma unroll
    for (int c=0;c<4;++c){
      size_t col = n0 + wc*64 + c*16 + la;
      #pragma unroll
      for (int r=0;r<4;++r){
        size_t row = i0 + wr*64 + h*16 + lg*4 + r;
        float v = acc[h][c][r];
        if (MODE == 0) outb[row*DM + col] = f2bf(v + bias[col]);
        else           outb[row*DM + col] = f2bf(v + bf2f(addb[row*DM + col]));
      }
    }
  }
}

// ---------------- merged QKV GEMM, 512 threads, BM=128 x BN=256 ----------------
__global__ __launch_bounds__(512) void k_gemm3(const short* __restrict__ A, const short* __restrict__ Bt,
       const short* __restrict__ addb, short* __restrict__ q, short* __restrict__ k, short* __restrict__ v){
  __shared__ short As[128*32];   // 8 KiB
  __shared__ short Bs[256*32];   // 16 KiB
  int t = threadIdx.x;
  int by = blockIdx.y;
  short* outb = (by < 2) ? q : (by < 4) ? k : v;
  size_t i0 = (size_t)blockIdx.x*128;
  size_t n0 = (size_t)by*256;          // row into 1536-row concat
  size_t c0 = (size_t)(by & 1)*256;    // output col base
  int w = t >> 6, l = t & 63, la = l & 15, lg = l >> 4;
  int wr = w >> 2, wc = w & 3;         // 2 x 4 waves: 64 rows x 64 cols each
  int rch8 = (lg ^ ((la>>1)&3))*8;
  f32x4 acc[4][4];
  #pragma unroll
  for (int h=0;h<4;++h)
    #pragma unroll
    for (int c=0;c<4;++c) acc[h][c] = (f32x4){0.f,0.f,0.f,0.f};
  int srow = t >> 2; int sk8 = SWZ_SK8(t);    // srow 0..127
  const short* Ab  = A  + (i0 + srow)*DM + sk8;
  const short* Bb  = Bt + (n0 + srow)*DM + sk8;
  const short* Bb2 = Bt + (n0 + 128 + srow)*DM + sk8;
  short* Asd = &As[t*8];
  short* Bsd = &Bs[t*8];  short* Bsd2 = &Bs[4096 + t*8];
  for (int k0 = 0; k0 < DM; k0 += 32){
    gload16(Ab  + k0, Asd);
    gload16(Bb  + k0, Bsd);
    gload16(Bb2 + k0, Bsd2);
    __syncthreads();
    s16x8 af[4], bg[4];
    #pragma unroll
    for (int h=0;h<4;++h) af[h] = *(const s16x8*)&As[(wr*64 + h*16 + la)*32 + rch8];
    #pragma unroll
    for (int c=0;c<4;++c) bg[c] = *(const s16x8*)&Bs[(wc*64 + c*16 + la)*32 + rch8];
    #pragma unroll
    for (int h=0;h<4;++h)
      #pragma unroll
      for (int c=0;c<4;++c)
        acc[h][c] = __builtin_amdgcn_mfma_f32_16x16x32_bf16(af[h], bg[c], acc[h][c], 0, 0, 0);
    __syncthreads();
  }
  #pragma unroll
  for (int h=0;h<4;++h){
    #pragma unroll
    for (int c=0;c<4;++c){
      size_t col = c0 + wc*64 + c*16 + la;
      #pragma unroll
      for (int r=0;r<4;++r){
        size_t row = i0 + wr*64 + h*16 + lg*4 + r;
        outb[row*DM + col] = f2bf(acc[h][c][r] + bf2f(addb[row*DM + col]));
      }
    }
  }
}

// ---------------- transpose ve -> vt[b][d][j] ----------------
__global__ __launch_bounds__(256) void k_vt(const short* __restrict__ ve, short* __restrict__ vt){
  int j0 = blockIdx.x*32, d0 = blockIdx.y*32, b = blockIdx.z;
  __shared__ short tile[32][36];
  int t = threadIdx.x;
  int r = t >> 3, c4 = (t & 7)*4;
  const short* vb = ve + (size_t)b*NN*DM;
  *(s16x4*)&tile[r][c4] = *(const s16x4*)&vb[(size_t)(j0+r)*DM + d0 + c4];
  __syncthreads();
  s16x4 o;
  #pragma unroll
  for (int e=0;e<4;++e) o[e] = tile[c4+e][r];
  short* ob = vt + (size_t)b*DM*NN;
  *(s16x4*)&ob[(size_t)(d0+r)*NN + j0 + c4] = o;
}

// ---------------- S-GEMM + exp, BM=256 x BN=128, 512 threads, BK=64 ----------------
// Taller tile: B(ke) re-read x8 instead of x16 -> L3 traffic 512->384 MB.
__global__ __launch_bounds__(512) void k_sexp(const short* __restrict__ qe, const short* __restrict__ ke,
       short* __restrict__ pbuf, float* __restrict__ lsum_part){
  __shared__ short As[256*64];   // 32 KiB
  __shared__ short Bs[128*64];   // 16 KiB
  int bid = blockIdx.x;
  int b = bid & 7;
  int r2 = bid >> 3;                 // 0..127
  int ti = r2 & 7, tj = r2 >> 3;     // 8 i-tiles of 256, 16 j-tiles of 128
  size_t i0 = (size_t)ti*256;
  size_t j0 = (size_t)tj*128;
  const short* A  = qe + (size_t)b*NN*DM;
  const short* Bt = ke + (size_t)b*NN*DM;
  int t = threadIdx.x;
  int w = t >> 6, l = t & 63, la = l & 15, lg = l >> 4;
  int wr = w >> 1, wc = w & 1;       // 4x2 waves: 64 rows x 64 cols each
  int rs8_0 = ((lg     ) ^ (la&7))*8;
  int rs8_1 = ((lg + 4 ) ^ (la&7))*8;
  f32x4 acc[4][4];
  #pragma unroll
  for (int h=0;h<4;++h)
    #pragma unroll
    for (int c=0;c<4;++c) acc[h][c] = (f32x4){0.f,0.f,0.f,0.f};
  int srow0 = t >> 3;                          // 0..63
  int gch8  = (((t&7) ^ ((t>>3)&7)))*8;        // pre-swizzled global chunk (row&7 = srow0&7)
  const short* Abase = A  + (i0 + srow0)*DM + gch8;
  const short* Bbase = Bt + (j0 + srow0)*DM + gch8;
  for (int k0 = 0; k0 < DM; k0 += 64){
    #pragma unroll
    for (int q = 0; q < 4; ++q)
      gload16(Abase + (size_t)(q*64)*DM + k0, &As[(q*512 + t)*8]);
    #pragma unroll
    for (int q = 0; q < 2; ++q)
      gload16(Bbase + (size_t)(q*64)*DM + k0, &Bs[(q*512 + t)*8]);
    __syncthreads();
    #pragma unroll
    for (int s = 0; s < 2; ++s){
      int rs8 = s ? rs8_1 : rs8_0;
      s16x8 af[4], bg[4];
      #pragma unroll
      for (int h=0;h<4;++h) af[h] = *(const s16x8*)&As[(wr*64 + h*16 + la)*64 + rs8];
      #pragma unroll
      for (int c=0;c<4;++c) bg[c] = *(const s16x8*)&Bs[(wc*64 + c*16 + la)*64 + rs8];
      #pragma unroll
      for (int h=0;h<4;++h)
        #pragma unroll
        for (int c=0;c<4;++c)
          acc[h][c] = __builtin_amdgcn_mfma_f32_16x16x32_bf16(af[h], bg[c], acc[h][c], 0, 0, 0);
    }
    __syncthreads();
  }
  const float scale = 0.044194173824159216f;  // 1/sqrt(512)
  short* pb = pbuf + (size_t)b*NN*NN;
  float rsum[4][4];
  #pragma unroll
  for (int h=0;h<4;++h)
    #pragma unroll
    for (int r=0;r<4;++r) rsum[h][r] = 0.f;
  #pragma unroll
  for (int h=0;h<4;++h){
    #pragma unroll
    for (int c=0;c<4;++c){
      size_t col = j0 + wc*64 + c*16 + la;
      #pragma unroll
      for (int r=0;r<4;++r){
        size_t row = i0 + wr*64 + h*16 + lg*4 + r;
        float p = __expf(acc[h][c][r]*scale);
        rsum[h][r] += p;
        pb[row*NN + col] = f2bf(p);
      }
    }
  }
  #pragma unroll
  for (int m = 1; m < 16; m <<= 1){
    #pragma unroll
    for (int h=0;h<4;++h)
      #pragma unroll
      for (int r=0;r<4;++r) rsum[h][r] += __shfl_xor(rsum[h][r], m);
  }
  if (la == 0){
    float* lp = lsum_part + (size_t)(tj*2 + wc)*ROWS + (size_t)b*NN;
    #pragma unroll
    for (int h=0;h<4;++h)
      #pragma unroll
      for (int r=0;r<4;++r)
        lp[i0 + wr*64 + h*16 + lg*4 + r] = rsum[h][r];
  }
}

// ---------------- PV GEMM, K=2048, BM=128 x BN=128, 512 threads, BK=64; lsum fused ----------------
__global__ __launch_bounds__(512) void k_pv(const short* __restrict__ pbuf, const short* __restrict__ vt,
        const float* __restrict__ lsum_part, float* __restrict__ attn){
  __shared__ short As[128*64];   // 16 KiB
  __shared__ short Bs[128*64];   // 16 KiB
  __shared__ float linv_lds[128];
  int bid = blockIdx.x;
  int b = bid & 7;
  int r2 = bid >> 3;                 // 0..63
  int ti = r2 & 15, tn = r2 >> 4;    // 16 i-tiles, 4 d-tiles of 128
  size_t i0 = (size_t)ti*128;
  size_t n0 = (size_t)tn*128;
  const short* A  = pbuf + (size_t)b*NN*NN;
  const short* Bt = vt + (size_t)b*DM*NN;
  int t = threadIdx.x;
  int w = t >> 6, l = t & 63, la = l & 15, lg = l >> 4;
  int wr = w >> 1, wc = w & 1;
  int rs8_0 = ((lg     ) ^ (la&7))*8;
  int rs8_1 = ((lg + 4 ) ^ (la&7))*8;
  if (t < 128){
    const float* lp = lsum_part + (size_t)b*NN + i0 + t;
    float s = 0.f;
    #pragma unroll
    for (int i = 0; i < 32; ++i) s += lp[(size_t)i*ROWS];
    linv_lds[t] = 1.0f/s;
  }
  f32x4 acc[2][4];
  #pragma unroll
  for (int h=0;h<2;++h)
    #pragma unroll
    for (int c=0;c<4;++c) acc[h][c] = (f32x4){0.f,0.f,0.f,0.f};
  int srow0 = t >> 3;                          // 0..63
  int gch8  = (((t&7) ^ ((t>>3)&7)))*8;
  const short* Abase = A  + (i0 + srow0)*NN + gch8;
  const short* Bbase = Bt + (n0 + srow0)*NN + gch8;
  for (int k0 = 0; k0 < NN; k0 += 64){
    #pragma unroll
    for (int q = 0; q < 2; ++q){
      gload16(Abase + (size_t)(q*64)*NN + k0, &As[(q*512 + t)*8]);
      gload16(Bbase + (size_t)(q*64)*NN + k0, &Bs[(q*512 + t)*8]);
    }
    __syncthreads();
    #pragma unroll
    for (int s = 0; s < 2; ++s){
      int rs8 = s ? rs8_1 : rs8_0;
      s16x8 af[2], bg[4];
      #pragma unroll
      for (int h=0;h<2;++h) af[h] = *(const s16x8*)&As[(wr*32 + h*16 + la)*64 + rs8];
      #pragma unroll
      for (int c=0;c<4;++c) bg[c] = *(const s16x8*)&Bs[(wc*64 + c*16 + la)*64 + rs8];
      #pragma unroll
      for (int h=0;h<2;++h)
        #pragma unroll
        for (int c=0;c<4;++c)
          acc[h][c] = __builtin_amdgcn_mfma_f32_16x16x32_bf16(af[h], bg[c], acc[h][c], 0, 0, 0);
    }
    __syncthreads();
  }
  #pragma unroll
  for (int h=0;h<2;++h){
    #pragma unroll
    for (int c=0;c<4;++c){
      size_t col = n0 + wc*64 + c*16 + la;
      #pragma unroll
      for (int r=0;r<4;++r){
        int rl = wr*32 + h*16 + lg*4 + r;
        attn[(size_t)b*NN*DM + (i0 + rl)*DM + col] = acc[h][c][r] * linv_lds[rl];
      }
    }
  }
}

// ---------------- res = attn@W2t^T + b2 + feat (MFMA, BM=64), A reg-staged f32->bf16 ----------------
__global__ __launch_bounds__(256) void k_res(const float* __restrict__ attn, const short* __restrict__ W2t,
       const float* __restrict__ b2, const float* __restrict__ feat, float* __restrict__ res){
  __shared__ short As[64*32];
  __shared__ short Bs[64*32];
  int t = threadIdx.x;
  size_t i0 = (size_t)blockIdx.x*64;
  int w = t >> 6, l = t & 63, la = l & 15, lg = l >> 4;
  int rch8 = (lg ^ ((la>>1)&3))*8;
  f32x4 acc[4];
  #pragma unroll
  for (int c=0;c<4;++c) acc[c] = (f32x4){0.f,0.f,0.f,0.f};
  int srow = t >> 2;
  int ch = t & 3;
  int dsw8 = (ch ^ ((srow>>1)&3))*8;          // swizzled LDS chunk for A (matches rch8 read)
  int sk8 = SWZ_SK8(t);
  const float* Arow = attn + (i0 + srow)*DM + ch*8;
  for (int k0 = 0; k0 < DM; k0 += 32){
    f32x4 a0 = *(const f32x4*)&Arow[k0];
    f32x4 a1 = *(const f32x4*)&Arow[k0 + 4];
    s16x8 ab;
    #pragma unroll
    for (int e=0;e<4;++e){ ab[e] = f2bf(a0[e]); ab[4+e] = f2bf(a1[e]); }
    *(s16x8*)&As[srow*32 + dsw8] = ab;
    gload16(W2t + (size_t)srow*DM + k0 + sk8, &Bs[t*8]);
    __syncthreads();
    s16x8 af, bg[4];
    af = *(const s16x8*)&As[(w*16 + la)*32 + rch8];
    #pragma unroll
    for (int c=0;c<4;++c) bg[c] = *(const s16x8*)&Bs[(c*16 + la)*32 + rch8];
    #pragma unroll
    for (int c=0;c<4;++c)
      acc[c] = __builtin_amdgcn_mfma_f32_16x16x32_bf16(af, bg[c], acc[c], 0, 0, 0);
    __syncthreads();
  }
  #pragma unroll
  for (int c=0;c<4;++c){
    int col = c*16 + la;
    #pragma unroll
    for (int r=0;r<4;++r){
      size_t row = i0 + w*16 + lg*4 + r;
      res[row*DP + col] = acc[c][r] + b2[col] + feat[row*DP + col];
    }
  }
}

extern "C" void kernel_launch(void* const* d_in, const int* in_sizes, int n_in,
                              void* d_out, int out_size, void* d_ws, size_t ws_size,
                              hipStream_t stream){
  const float* xyz  = (const float*)d_in[0];
  const float* feat = (const float*)d_in[1];
  const float* W1   = (const float*)d_in[2];
  const float* b1   = (const float*)d_in[3];
  const float* W2   = (const float*)d_in[4];
  const float* b2   = (const float*)d_in[5];
  const float* Wd1  = (const float*)d_in[6];
  const float* bd1  = (const float*)d_in[7];
  const float* Wd2  = (const float*)d_in[8];
  const float* bd2  = (const float*)d_in[9];
  const float* Wq   = (const float*)d_in[10];
  const float* Wk   = (const float*)d_in[11];
  const float* Wv   = (const float*)d_in[12];

  char* ws = (char*)d_ws;                        // max used: 153 MiB
  int*   kidx      = (int*)  (ws + (1ull<<20));  // 1MiB; dead after k_g
  float* kw        = (float*)(ws + (2ull<<20));  // 1MiB; dead after k_g
  float* wsum      = (float*)(ws + (3ull<<20));  // 64KiB; dead after k_g
  float* lsum_part = (float*)(ws + (1ull<<20));  // 2MiB overlay (32 x 16384 f32), after k_g
  short* Wqt   = (short*)(ws + (4ull<<20));      // contiguous: Wqt,Wkt,Wvt,Wd2t (QKV concat rows 0..1535)
  short* Wkt   = Wqt + (size_t)DM*DM;
  short* Wvt   = Wkt + (size_t)DM*DM;
  short* Wd2t  = Wvt + (size_t)DM*DM;
  short* W1t   = (short*)(ws + (6ull<<20));      // 64KiB
  short* W2t   = (short*)(ws + (6ull<<20) + 131072);
  short* featb = (short*)(ws + (7ull<<20));      // 2MiB: 7..9
  short* qe    = (short*)(ws + (9ull<<20));      // 16MiB: 9..25
  short* g     = (short*)(ws + (25ull<<20));     // 16MiB: 25..41; reused as ke
  short* x     = (short*)(ws + (41ull<<20));     // 16MiB: 41..57; reused as vt
  short* wab   = (short*)(ws + (57ull<<20));     // 16MiB: 57..73
  short* ve    = (short*)(ws + (73ull<<20));     // 16MiB: 73..89; dead after k_vt
  short* pbuf  = (short*)(ws + (89ull<<20));     // 64MiB: 89..153 (all 8 batches)
  short* ke = g; short* vt = x;

  float* res  = (float*)d_out;
  float* attn = (float*)d_out + (size_t)ROWS*DP;

  k_knn  <<<ROWS/4, 256, 0, stream>>>(xyz, kidx, kw, wsum);
  k_prep2<<<(4*DM*DM + 2*DM*DP + ROWS*DP)/256, 256, 0, stream>>>(
           Wq, Wk, Wv, Wd2, W1, W2, feat, Wqt, Wkt, Wvt, Wd2t, W1t, W2t, featb);
  k_g    <<<ROWS/4, 256, 0, stream>>>(xyz, Wd1, bd1, kidx, kw, wsum, g);
  k_gemm<DP,0>  <<<dim3(ROWS/128, DM/128), 256, 0, stream>>>(featb, W1t, b1, nullptr, x);
  k_gemm<DM,0>  <<<dim3(ROWS/128, DM/128), 256, 0, stream>>>(g, Wd2t, bd2, nullptr, wab);
  k_gemm3       <<<dim3(ROWS/128, 6), 512, 0, stream>>>(x, Wqt, wab, qe, ke, ve);
  k_vt   <<<dim3(NN/32, DM/32, BB), 256, 0, stream>>>(ve, vt);
  // attention: single pass over all 8 batches (pbuf 64 MiB), BK=64, lsum fused into pv
  k_sexp <<<1024, 512, 0, stream>>>(qe, ke, pbuf, lsum_part);
  k_pv   <<<512, 512, 0, stream>>>(pbuf, vt, lsum_part, attn);
  k_res  <<<ROWS/64, 256, 0, stream>>>(attn, W2t, b2, feat, res);
}

// Round 22
// 233.471 us; speedup vs baseline: 1.0641x; 1.0196x over previous
//
#include <hip/hip_runtime.h>
#include <hip/hip_bf16.h>

#define BB 8
#define NN 2048
#define DP 64
#define DM 512
#define KNNK 16
#define ROWS (BB*NN)   // 16384

// pre-swizzled staging chunk for thread t (pairs with RCH8 read swizzle) -- 32-short rows
#define SWZ_SK8(t) (((((t)&3) ^ (((t)>>3)&3)))*8)

typedef __attribute__((ext_vector_type(8))) short s16x8;
typedef __attribute__((ext_vector_type(4))) short s16x4;
typedef __attribute__((ext_vector_type(4))) float f32x4;

__device__ __forceinline__ float bf2f(short u){
  union { unsigned int i; float f; } v; v.i = ((unsigned int)(unsigned short)u) << 16; return v.f;
}
__device__ __forceinline__ short f2bf(float f){
  __hip_bfloat16 h = __float2bfloat16(f);    // RNE
  return *reinterpret_cast<short*>(&h);
}

// global -> LDS direct (16B per lane)
__device__ __forceinline__ void gload16(const void* g, void* l){
  __builtin_amdgcn_global_load_lds(
      (const __attribute__((address_space(1))) void*)(__UINTPTR_TYPE__)g,
      (__attribute__((address_space(3))) void*)(__UINTPTR_TYPE__)l, 16, 0, 0);
}

// wave-wide min of u32 via DPP (row_shr 1/2/4/8, row_bcast 15/31), broadcast via readlane
__device__ __forceinline__ unsigned wave_min_u32(unsigned v){
  v = min(v, (unsigned)__builtin_amdgcn_update_dpp((int)v, (int)v, 0x111, 0xF, 0xF, false));
  v = min(v, (unsigned)__builtin_amdgcn_update_dpp((int)v, (int)v, 0x112, 0xF, 0xF, false));
  v = min(v, (unsigned)__builtin_amdgcn_update_dpp((int)v, (int)v, 0x114, 0xF, 0xF, false));
  v = min(v, (unsigned)__builtin_amdgcn_update_dpp((int)v, (int)v, 0x118, 0xF, 0xF, false));
  v = min(v, (unsigned)__builtin_amdgcn_update_dpp((int)v, (int)v, 0x142, 0xF, 0xF, false));
  v = min(v, (unsigned)__builtin_amdgcn_update_dpp((int)v, (int)v, 0x143, 0xF, 0xF, false));
  return (unsigned)__builtin_amdgcn_readlane((int)v, 63);
}

// ---------------- exact knn (sq fused): wave-per-row, packed keys, top-3 tournament ----------------
__global__ __launch_bounds__(256) void k_knn(const float* __restrict__ xyz,
        int* __restrict__ kidx, float* __restrict__ kw, float* __restrict__ wsum){
  int row = blockIdx.x*4 + (threadIdx.x >> 6);
  int l = threadIdx.x & 63;
  int b = row >> 11; int i = row & (NN-1);
  const float* xb = xyz + (size_t)b*NN*3;
  float xi0 = xb[3*i], xi1 = xb[3*i+1], xi2 = xb[3*i+2];
  float sqi = xi0*xi0 + xi1*xi1 + xi2*xi2;
  unsigned key[32];
  unsigned m1 = 0xFFFFFFFFu, m2 = 0xFFFFFFFFu, m3 = 0xFFFFFFFFu;
  #pragma unroll
  for (int e = 0; e < 32; ++e){
    int j = e*64 + l;
    float x0 = xb[3*j], x1 = xb[3*j+1], x2 = xb[3*j+2];
    float sqj = x0*x0 + x1*x1 + x2*x2;
    float d = sqi + sqj - 2.0f*(xi0*x0 + xi1*x1 + xi2*x2);
    d = fmaxf(d, 0.f);
    union { float f; unsigned u; } cv; cv.f = d;
    unsigned k = (cv.u & 0xFFFFF800u) | (unsigned)j;
    key[e] = k;
    unsigned r1 = max(k, m1);  m1 = min(k, m1);
    unsigned r2 = max(r1, m2); m2 = min(r1, m2);
    m3 = min(r2, m3);
  }
  float wacc = 0.f;
  for (int sel = 0; sel < KNNK; ++sel){
    unsigned g = wave_min_u32(m1);          // uniform
    unsigned j = g & 2047u;
    union { unsigned u; float f; } dv; dv.u = g & 0xFFFFF800u;
    float wg = 1.0f/(dv.f + 1e-6f);
    wacc += wg;
    if (l == 0){
      kidx[(size_t)row*KNNK + sel] = (int)j;
      kw[(size_t)row*KNNK + sel] = wg;
    }
    bool win = (m1 == g);                   // at most one lane (keys unique)
    if (win){ m1 = m2; m2 = m3; m3 = 0xFFFFFFFFu; }
    if (__any(win && m1 == 0xFFFFFFFFu)){   // rare: winner exhausted its top-3
      if (win && m1 == 0xFFFFFFFFu){
        unsigned mm = 0xFFFFFFFFu;
        #pragma unroll
        for (int e = 0; e < 32; ++e){
          unsigned k2 = key[e];
          mm = min(mm, (k2 > g) ? k2 : 0xFFFFFFFFu);
        }
        m1 = mm;
      }
    }
  }
  if (l == 0) wsum[row] = wacc;
}

// ---------------- one-shot prep: transposed bf16 weights + featb ----------------
__global__ void k_prep2(const float* __restrict__ Wq, const float* __restrict__ Wk,
                        const float* __restrict__ Wv, const float* __restrict__ Wd2,
                        const float* __restrict__ W1, const float* __restrict__ W2,
                        const float* __restrict__ feat,
                        short* __restrict__ Wqt, short* __restrict__ Wkt,
                        short* __restrict__ Wvt, short* __restrict__ Wd2t,
                        short* __restrict__ W1t, short* __restrict__ W2t,
                        short* __restrict__ featb){
  int idx = blockIdx.x*256 + threadIdx.x;
  if (idx < 4*DM*DM){
    int m = idx >> 18;
    int r = idx & (DM*DM-1);
    int n = r >> 9, k = r & 511;
    const float* W = (m==0)?Wq:(m==1)?Wk:(m==2)?Wv:Wd2;
    short* Wt = (m==0)?Wqt:(m==1)?Wkt:(m==2)?Wvt:Wd2t;
    Wt[r] = f2bf(W[k*DM + n]);
  } else if (idx < 4*DM*DM + DM*DP){
    int r = idx - 4*DM*DM;
    int n = r >> 6, k = r & 63;
    W1t[r] = f2bf(W1[(size_t)k*DM + n]);
  } else if (idx < 4*DM*DM + 2*DM*DP){
    int r = idx - 4*DM*DM - DM*DP;
    int n = r >> 9, k = r & 511;
    W2t[r] = f2bf(W2[(size_t)k*DP + n]);
  } else {
    int r = idx - 4*DM*DM - 2*DM*DP;
    featb[r] = f2bf(feat[r]);
  }
}

// ---------------- g = (sum_j w_j * relu(xyz[idx_j]@Wd1 + bd1)) / wsum, fused, bf16 ----------------
__global__ __launch_bounds__(256) void k_g(const float* __restrict__ xyz, const float* __restrict__ Wd1,
                   const float* __restrict__ bd1, const int* __restrict__ kidx,
                   const float* __restrict__ kw, const float* __restrict__ wsum, short* __restrict__ g){
  int bid = blockIdx.x;
  int p = ((bid&7)<<11) + ((bid>>3)<<2) + (threadIdx.x>>6);   // batch = bid&7 (XCD-pinned)
  int c8 = (threadIdx.x&63)*8;
  int b = p >> 11;
  const float* xbase = xyz + (size_t)b*NN*3;
  float wd0[8], wd1v[8], wd2v[8], bb[8];
  #pragma unroll
  for (int e=0;e<8;++e){
    wd0[e]  = Wd1[c8+e];
    wd1v[e] = Wd1[DM + c8+e];
    wd2v[e] = Wd1[2*DM + c8+e];
    bb[e]   = bd1[c8+e];
  }
  int jj[KNNK]; float wj[KNNK];
  #pragma unroll
  for (int j = 0; j < KNNK; ++j){
    jj[j] = kidx[(size_t)p*KNNK + j];
    wj[j] = kw[(size_t)p*KNNK + j];
  }
  float acc[8] = {0,0,0,0,0,0,0,0};
  #pragma unroll
  for (int j = 0; j < KNNK; ++j){
    float x0 = xbase[3*jj[j]], x1 = xbase[3*jj[j]+1], x2 = xbase[3*jj[j]+2];
    float w = wj[j];
    #pragma unroll
    for (int e=0;e<8;++e){
      float v = fmaf(x0, wd0[e], fmaf(x1, wd1v[e], fmaf(x2, wd2v[e], bb[e])));
      acc[e] = fmaf(w, fmaxf(v, 0.f), acc[e]);
    }
  }
  float inv = 1.0f/wsum[p];
  s16x8 o;
  #pragma unroll
  for (int e=0;e<8;++e) o[e] = f2bf(acc[e]*inv);
  *(s16x8*)&g[(size_t)p*DM + c8] = o;
}

// ---------------- bf16 MFMA GEMM (BM=128,BN=128), XOR-swizzled LDS (BK=32) ----------------
template<int KD, int MODE>
__global__ __launch_bounds__(256) void k_gemm(const short* __restrict__ A, const short* __restrict__ Bt,
       const float* __restrict__ bias, const short* __restrict__ addb, short* __restrict__ outb){
  __shared__ short As[128*32];
  __shared__ short Bs[128*32];
  int t = threadIdx.x;
  size_t i0 = (size_t)blockIdx.x*128, n0 = (size_t)blockIdx.y*128;
  int w = t >> 6, l = t & 63, la = l & 15, lg = l >> 4;
  int wr = w >> 1, wc = w & 1;
  int rch8 = (lg ^ ((la>>1)&3))*8;
  f32x4 acc[4][4];
  #pragma unroll
  for (int h=0;h<4;++h)
    #pragma unroll
    for (int c=0;c<4;++c) acc[h][c] = (f32x4){0.f,0.f,0.f,0.f};
  int srow = t >> 2; int sk8 = SWZ_SK8(t);
  const short* Ab  = A  + (i0 + srow)*KD + sk8;
  const short* Ab2 = A  + (i0 + 64 + srow)*KD + sk8;
  const short* Bb  = Bt + (n0 + srow)*KD + sk8;
  const short* Bb2 = Bt + (n0 + 64 + srow)*KD + sk8;
  short* Asd  = &As[t*8];      short* Asd2 = &As[2048 + t*8];
  short* Bsd  = &Bs[t*8];      short* Bsd2 = &Bs[2048 + t*8];
  for (int k0 = 0; k0 < KD; k0 += 32){
    gload16(Ab  + k0, Asd);
    gload16(Ab2 + k0, Asd2);
    gload16(Bb  + k0, Bsd);
    gload16(Bb2 + k0, Bsd2);
    __syncthreads();
    s16x8 af[4], bg[4];
    #pragma unroll
    for (int h=0;h<4;++h) af[h] = *(const s16x8*)&As[(wr*64 + h*16 + la)*32 + rch8];
    #pragma unroll
    for (int c=0;c<4;++c) bg[c] = *(const s16x8*)&Bs[(wc*64 + c*16 + la)*32 + rch8];
    #pragma unroll
    for (int h=0;h<4;++h)
      #pragma unroll
      for (int c=0;c<4;++c)
        acc[h][c] = __builtin_amdgcn_mfma_f32_16x16x32_bf16(af[h], bg[c], acc[h][c], 0, 0, 0);
    __syncthreads();
  }
  #pragma unroll
  for (int h=0;h<4;++h){
    #pragma unroll
    for (int c=0;c<4;++c){
      size_t col = n0 + wc*64 + c*16 + la;
      #pragma unroll
      for (int r=0;r<4;++r){
        size_t row = i0 + wr*64 + h*16 + lg*4 + r;
        float v = acc[h][c][r];
        if (MODE == 0) outb[row*DM + col] = f2bf(v + bias[col]);
        else           outb[row*DM + col] = f2bf(v + bf2f(addb[row*DM + col]));
      }
    }
  }
}

// ---------------- bf16 MFMA GEMM (BM=128,BN=128), BK=64, 256 threads (R16 sexp structure) ----------------
template<int MODE>
__global__ __launch_bounds__(256) void k_gemm64(const short* __restrict__ A, const short* __restrict__ Bt,
       const float* __restrict__ bias, const short* __restrict__ addb, short* __restrict__ outb){
  __shared__ short As[128*64];   // 16 KiB
  __shared__ short Bs[128*64];   // 16 KiB
  int t = threadIdx.x;
  size_t i0 = (size_t)blockIdx.x*128, n0 = (size_t)blockIdx.y*128;
  int w = t >> 6, l = t & 63, la = l & 15, lg = l >> 4;
  int wr = w >> 1, wc = w & 1;
  int rs8_0 = ((lg     ) ^ (la&7))*8;
  int rs8_1 = ((lg + 4 ) ^ (la&7))*8;
  f32x4 acc[4][4];
  #pragma unroll
  for (int h=0;h<4;++h)
    #pragma unroll
    for (int c=0;c<4;++c) acc[h][c] = (f32x4){0.f,0.f,0.f,0.f};
  int srow0 = t >> 3;                          // 0..31
  int gch8  = (((t&7) ^ ((t>>3)&7)))*8;
  const short* Abase = A  + (i0 + srow0)*DM + gch8;
  const short* Bbase = Bt + (n0 + srow0)*DM + gch8;
  for (int k0 = 0; k0 < DM; k0 += 64){
    #pragma unroll
    for (int q = 0; q < 4; ++q){
      gload16(Abase + (size_t)(q*32)*DM + k0, &As[(q*256 + t)*8]);
      gload16(Bbase + (size_t)(q*32)*DM + k0, &Bs[(q*256 + t)*8]);
    }
    __syncthreads();
    #pragma unroll
    for (int s = 0; s < 2; ++s){
      int rs8 = s ? rs8_1 : rs8_0;
      s16x8 af[4], bg[4];
      #pragma unroll
      for (int h=0;h<4;++h) af[h] = *(const s16x8*)&As[(wr*64 + h*16 + la)*64 + rs8];
      #pragma unroll
      for (int c=0;c<4;++c) bg[c] = *(const s16x8*)&Bs[(wc*64 + c*16 + la)*64 + rs8];
      #pragma unroll
      for (int h=0;h<4;++h)
        #pragma unroll
        for (int c=0;c<4;++c)
          acc[h][c] = __builtin_amdgcn_mfma_f32_16x16x32_bf16(af[h], bg[c], acc[h][c], 0, 0, 0);
    }
    __syncthreads();
  }
  #pragma unroll
  for (int h=0;h<4;++h){
    #pragma unroll
    for (int c=0;c<4;++c){
      size_t col = n0 + wc*64 + c*16 + la;
      #pragma unroll
      for (int r=0;r<4;++r){
        size_t row = i0 + wr*64 + h*16 + lg*4 + r;
        float v = acc[h][c][r];
        if (MODE == 0) outb[row*DM + col] = f2bf(v + bias[col]);
        else           outb[row*DM + col] = f2bf(v + bf2f(addb[row*DM + col]));
      }
    }
  }
}

// ---------------- merged QKV GEMM, 512 threads, BM=128 x BN=256, BK=64 ----------------
__global__ __launch_bounds__(512) void k_gemm3(const short* __restrict__ A, const short* __restrict__ Bt,
       const short* __restrict__ addb, short* __restrict__ q, short* __restrict__ k, short* __restrict__ v){
  __shared__ short As[128*64];   // 16 KiB
  __shared__ short Bs[256*64];   // 32 KiB
  int t = threadIdx.x;
  int by = blockIdx.y;
  short* outb = (by < 2) ? q : (by < 4) ? k : v;
  size_t i0 = (size_t)blockIdx.x*128;
  size_t n0 = (size_t)by*256;          // row into 1536-row concat
  size_t c0 = (size_t)(by & 1)*256;    // output col base
  int w = t >> 6, l = t & 63, la = l & 15, lg = l >> 4;
  int wr = w >> 2, wc = w & 3;         // 2 x 4 waves: 64 rows x 64 cols each
  int rs8_0 = ((lg     ) ^ (la&7))*8;
  int rs8_1 = ((lg + 4 ) ^ (la&7))*8;
  f32x4 acc[4][4];
  #pragma unroll
  for (int h=0;h<4;++h)
    #pragma unroll
    for (int c=0;c<4;++c) acc[h][c] = (f32x4){0.f,0.f,0.f,0.f};
  int srow0 = t >> 3;                          // 0..63
  int gch8  = (((t&7) ^ ((t>>3)&7)))*8;        // pre-swizzled global chunk (row&7 invariant mod 64)
  const short* Abase = A  + (i0 + srow0)*DM + gch8;
  const short* Bbase = Bt + (n0 + srow0)*DM + gch8;
  for (int k0 = 0; k0 < DM; k0 += 64){
    #pragma unroll
    for (int qq = 0; qq < 2; ++qq)
      gload16(Abase + (size_t)(qq*64)*DM + k0, &As[(qq*512 + t)*8]);
    #pragma unroll
    for (int qq = 0; qq < 4; ++qq)
      gload16(Bbase + (size_t)(qq*64)*DM + k0, &Bs[(qq*512 + t)*8]);
    __syncthreads();
    #pragma unroll
    for (int s = 0; s < 2; ++s){
      int rs8 = s ? rs8_1 : rs8_0;
      s16x8 af[4], bg[4];
      #pragma unroll
      for (int h=0;h<4;++h) af[h] = *(const s16x8*)&As[(wr*64 + h*16 + la)*64 + rs8];
      #pragma unroll
      for (int c=0;c<4;++c) bg[c] = *(const s16x8*)&Bs[(wc*64 + c*16 + la)*64 + rs8];
      #pragma unroll
      for (int h=0;h<4;++h)
        #pragma unroll
        for (int c=0;c<4;++c)
          acc[h][c] = __builtin_amdgcn_mfma_f32_16x16x32_bf16(af[h], bg[c], acc[h][c], 0, 0, 0);
    }
    __syncthreads();
  }
  #pragma unroll
  for (int h=0;h<4;++h){
    #pragma unroll
    for (int c=0;c<4;++c){
      size_t col = c0 + wc*64 + c*16 + la;
      #pragma unroll
      for (int r=0;r<4;++r){
        size_t row = i0 + wr*64 + h*16 + lg*4 + r;
        outb[row*DM + col] = f2bf(acc[h][c][r] + bf2f(addb[row*DM + col]));
      }
    }
  }
}

// ---------------- transpose ve -> vt[b][d][j] ----------------
__global__ __launch_bounds__(256) void k_vt(const short* __restrict__ ve, short* __restrict__ vt){
  int j0 = blockIdx.x*32, d0 = blockIdx.y*32, b = blockIdx.z;
  __shared__ short tile[32][36];
  int t = threadIdx.x;
  int r = t >> 3, c4 = (t & 7)*4;
  const short* vb = ve + (size_t)b*NN*DM;
  *(s16x4*)&tile[r][c4] = *(const s16x4*)&vb[(size_t)(j0+r)*DM + d0 + c4];
  __syncthreads();
  s16x4 o;
  #pragma unroll
  for (int e=0;e<4;++e) o[e] = tile[c4+e][r];
  short* ob = vt + (size_t)b*DM*NN;
  *(s16x4*)&ob[(size_t)(d0+r)*NN + j0 + c4] = o;
}

// ---------------- S-GEMM + exp, BM=256 x BN=128, 512 threads, BK=64 ----------------
__global__ __launch_bounds__(512) void k_sexp(const short* __restrict__ qe, const short* __restrict__ ke,
       short* __restrict__ pbuf, float* __restrict__ lsum_part){
  __shared__ short As[256*64];   // 32 KiB
  __shared__ short Bs[128*64];   // 16 KiB
  int bid = blockIdx.x;
  int b = bid & 7;
  int r2 = bid >> 3;                 // 0..127
  int ti = r2 & 7, tj = r2 >> 3;     // 8 i-tiles of 256, 16 j-tiles of 128
  size_t i0 = (size_t)ti*256;
  size_t j0 = (size_t)tj*128;
  const short* A  = qe + (size_t)b*NN*DM;
  const short* Bt = ke + (size_t)b*NN*DM;
  int t = threadIdx.x;
  int w = t >> 6, l = t & 63, la = l & 15, lg = l >> 4;
  int wr = w >> 1, wc = w & 1;       // 4x2 waves: 64 rows x 64 cols each
  int rs8_0 = ((lg     ) ^ (la&7))*8;
  int rs8_1 = ((lg + 4 ) ^ (la&7))*8;
  f32x4 acc[4][4];
  #pragma unroll
  for (int h=0;h<4;++h)
    #pragma unroll
    for (int c=0;c<4;++c) acc[h][c] = (f32x4){0.f,0.f,0.f,0.f};
  int srow0 = t >> 3;                          // 0..63
  int gch8  = (((t&7) ^ ((t>>3)&7)))*8;        // pre-swizzled global chunk (row&7 = srow0&7)
  const short* Abase = A  + (i0 + srow0)*DM + gch8;
  const short* Bbase = Bt + (j0 + srow0)*DM + gch8;
  for (int k0 = 0; k0 < DM; k0 += 64){
    #pragma unroll
    for (int q = 0; q < 4; ++q)
      gload16(Abase + (size_t)(q*64)*DM + k0, &As[(q*512 + t)*8]);
    #pragma unroll
    for (int q = 0; q < 2; ++q)
      gload16(Bbase + (size_t)(q*64)*DM + k0, &Bs[(q*512 + t)*8]);
    __syncthreads();
    #pragma unroll
    for (int s = 0; s < 2; ++s){
      int rs8 = s ? rs8_1 : rs8_0;
      s16x8 af[4], bg[4];
      #pragma unroll
      for (int h=0;h<4;++h) af[h] = *(const s16x8*)&As[(wr*64 + h*16 + la)*64 + rs8];
      #pragma unroll
      for (int c=0;c<4;++c) bg[c] = *(const s16x8*)&Bs[(wc*64 + c*16 + la)*64 + rs8];
      #pragma unroll
      for (int h=0;h<4;++h)
        #pragma unroll
        for (int c=0;c<4;++c)
          acc[h][c] = __builtin_amdgcn_mfma_f32_16x16x32_bf16(af[h], bg[c], acc[h][c], 0, 0, 0);
    }
    __syncthreads();
  }
  const float scale = 0.044194173824159216f;  // 1/sqrt(512)
  short* pb = pbuf + (size_t)b*NN*NN;
  float rsum[4][4];
  #pragma unroll
  for (int h=0;h<4;++h)
    #pragma unroll
    for (int r=0;r<4;++r) rsum[h][r] = 0.f;
  #pragma unroll
  for (int h=0;h<4;++h){
    #pragma unroll
    for (int c=0;c<4;++c){
      size_t col = j0 + wc*64 + c*16 + la;
      #pragma unroll
      for (int r=0;r<4;++r){
        size_t row = i0 + wr*64 + h*16 + lg*4 + r;
        float p = __expf(acc[h][c][r]*scale);
        rsum[h][r] += p;
        pb[row*NN + col] = f2bf(p);
      }
    }
  }
  #pragma unroll
  for (int m = 1; m < 16; m <<= 1){
    #pragma unroll
    for (int h=0;h<4;++h)
      #pragma unroll
      for (int r=0;r<4;++r) rsum[h][r] += __shfl_xor(rsum[h][r], m);
  }
  if (la == 0){
    float* lp = lsum_part + (size_t)(tj*2 + wc)*ROWS + (size_t)b*NN;
    #pragma unroll
    for (int h=0;h<4;++h)
      #pragma unroll
      for (int r=0;r<4;++r)
        lp[i0 + wr*64 + h*16 + lg*4 + r] = rsum[h][r];
  }
}

// ---------------- PV GEMM, K=2048, BM=128 x BN=128, 512 threads, BK=64; lsum fused ----------------
__global__ __launch_bounds__(512) void k_pv(const short* __restrict__ pbuf, const short* __restrict__ vt,
        const float* __restrict__ lsum_part, float* __restrict__ attn){
  __shared__ short As[128*64];   // 16 KiB
  __shared__ short Bs[128*64];   // 16 KiB
  __shared__ float linv_lds[128];
  int bid = blockIdx.x;
  int b = bid & 7;
  int r2 = bid >> 3;                 // 0..63
  int ti = r2 & 15, tn = r2 >> 4;    // 16 i-tiles, 4 d-tiles of 128
  size_t i0 = (size_t)ti*128;
  size_t n0 = (size_t)tn*128;
  const short* A  = pbuf + (size_t)b*NN*NN;
  const short* Bt = vt + (size_t)b*DM*NN;
  int t = threadIdx.x;
  int w = t >> 6, l = t & 63, la = l & 15, lg = l >> 4;
  int wr = w >> 1, wc = w & 1;
  int rs8_0 = ((lg     ) ^ (la&7))*8;
  int rs8_1 = ((lg + 4 ) ^ (la&7))*8;
  if (t < 128){
    const float* lp = lsum_part + (size_t)b*NN + i0 + t;
    float s = 0.f;
    #pragma unroll
    for (int i = 0; i < 32; ++i) s += lp[(size_t)i*ROWS];
    linv_lds[t] = 1.0f/s;
  }
  f32x4 acc[2][4];
  #pragma unroll
  for (int h=0;h<2;++h)
    #pragma unroll
    for (int c=0;c<4;++c) acc[h][c] = (f32x4){0.f,0.f,0.f,0.f};
  int srow0 = t >> 3;                          // 0..63
  int gch8  = (((t&7) ^ ((t>>3)&7)))*8;
  const short* Abase = A  + (i0 + srow0)*NN + gch8;
  const short* Bbase = Bt + (n0 + srow0)*NN + gch8;
  for (int k0 = 0; k0 < NN; k0 += 64){
    #pragma unroll
    for (int q = 0; q < 2; ++q){
      gload16(Abase + (size_t)(q*64)*NN + k0, &As[(q*512 + t)*8]);
      gload16(Bbase + (size_t)(q*64)*NN + k0, &Bs[(q*512 + t)*8]);
    }
    __syncthreads();
    #pragma unroll
    for (int s = 0; s < 2; ++s){
      int rs8 = s ? rs8_1 : rs8_0;
      s16x8 af[2], bg[4];
      #pragma unroll
      for (int h=0;h<2;++h) af[h] = *(const s16x8*)&As[(wr*32 + h*16 + la)*64 + rs8];
      #pragma unroll
      for (int c=0;c<4;++c) bg[c] = *(const s16x8*)&Bs[(wc*64 + c*16 + la)*64 + rs8];
      #pragma unroll
      for (int h=0;h<2;++h)
        #pragma unroll
        for (int c=0;c<4;++c)
          acc[h][c] = __builtin_amdgcn_mfma_f32_16x16x32_bf16(af[h], bg[c], acc[h][c], 0, 0, 0);
    }
    __syncthreads();
  }
  #pragma unroll
  for (int h=0;h<2;++h){
    #pragma unroll
    for (int c=0;c<4;++c){
      size_t col = n0 + wc*64 + c*16 + la;
      #pragma unroll
      for (int r=0;r<4;++r){
        int rl = wr*32 + h*16 + lg*4 + r;
        attn[(size_t)b*NN*DM + (i0 + rl)*DM + col] = acc[h][c][r] * linv_lds[rl];
      }
    }
  }
}

// ---------------- res = attn@W2t^T + b2 + feat (MFMA, BM=64), A reg-staged f32->bf16 ----------------
__global__ __launch_bounds__(256) void k_res(const float* __restrict__ attn, const short* __restrict__ W2t,
       const float* __restrict__ b2, const float* __restrict__ feat, float* __restrict__ res){
  __shared__ short As[64*32];
  __shared__ short Bs[64*32];
  int t = threadIdx.x;
  size_t i0 = (size_t)blockIdx.x*64;
  int w = t >> 6, l = t & 63, la = l & 15, lg = l >> 4;
  int rch8 = (lg ^ ((la>>1)&3))*8;
  f32x4 acc[4];
  #pragma unroll
  for (int c=0;c<4;++c) acc[c] = (f32x4){0.f,0.f,0.f,0.f};
  int srow = t >> 2;
  int ch = t & 3;
  int dsw8 = (ch ^ ((srow>>1)&3))*8;          // swizzled LDS chunk for A (matches rch8 read)
  int sk8 = SWZ_SK8(t);
  const float* Arow = attn + (i0 + srow)*DM + ch*8;
  for (int k0 = 0; k0 < DM; k0 += 32){
    f32x4 a0 = *(const f32x4*)&Arow[k0];
    f32x4 a1 = *(const f32x4*)&Arow[k0 + 4];
    s16x8 ab;
    #pragma unroll
    for (int e=0;e<4;++e){ ab[e] = f2bf(a0[e]); ab[4+e] = f2bf(a1[e]); }
    *(s16x8*)&As[srow*32 + dsw8] = ab;
    gload16(W2t + (size_t)srow*DM + k0 + sk8, &Bs[t*8]);
    __syncthreads();
    s16x8 af, bg[4];
    af = *(const s16x8*)&As[(w*16 + la)*32 + rch8];
    #pragma unroll
    for (int c=0;c<4;++c) bg[c] = *(const s16x8*)&Bs[(c*16 + la)*32 + rch8];
    #pragma unroll
    for (int c=0;c<4;++c)
      acc[c] = __builtin_amdgcn_mfma_f32_16x16x32_bf16(af, bg[c], acc[c], 0, 0, 0);
    __syncthreads();
  }
  #pragma unroll
  for (int c=0;c<4;++c){
    int col = c*16 + la;
    #pragma unroll
    for (int r=0;r<4;++r){
      size_t row = i0 + w*16 + lg*4 + r;
      res[row*DP + col] = acc[c][r] + b2[col] + feat[row*DP + col];
    }
  }
}

extern "C" void kernel_launch(void* const* d_in, const int* in_sizes, int n_in,
                              void* d_out, int out_size, void* d_ws, size_t ws_size,
                              hipStream_t stream){
  const float* xyz  = (const float*)d_in[0];
  const float* feat = (const float*)d_in[1];
  const float* W1   = (const float*)d_in[2];
  const float* b1   = (const float*)d_in[3];
  const float* W2   = (const float*)d_in[4];
  const float* b2   = (const float*)d_in[5];
  const float* Wd1  = (const float*)d_in[6];
  const float* bd1  = (const float*)d_in[7];
  const float* Wd2  = (const float*)d_in[8];
  const float* bd2  = (const float*)d_in[9];
  const float* Wq   = (const float*)d_in[10];
  const float* Wk   = (const float*)d_in[11];
  const float* Wv   = (const float*)d_in[12];

  char* ws = (char*)d_ws;                        // max used: 153 MiB
  int*   kidx      = (int*)  (ws + (1ull<<20));  // 1MiB; dead after k_g
  float* kw        = (float*)(ws + (2ull<<20));  // 1MiB; dead after k_g
  float* wsum      = (float*)(ws + (3ull<<20));  // 64KiB; dead after k_g
  float* lsum_part = (float*)(ws + (1ull<<20));  // 2MiB overlay (32 x 16384 f32), after k_g
  short* Wqt   = (short*)(ws + (4ull<<20));      // contiguous: Wqt,Wkt,Wvt,Wd2t (QKV concat rows 0..1535)
  short* Wkt   = Wqt + (size_t)DM*DM;
  short* Wvt   = Wkt + (size_t)DM*DM;
  short* Wd2t  = Wvt + (size_t)DM*DM;
  short* W1t   = (short*)(ws + (6ull<<20));      // 64KiB
  short* W2t   = (short*)(ws + (6ull<<20) + 131072);
  short* featb = (short*)(ws + (7ull<<20));      // 2MiB: 7..9
  short* qe    = (short*)(ws + (9ull<<20));      // 16MiB: 9..25
  short* g     = (short*)(ws + (25ull<<20));     // 16MiB: 25..41; reused as ke
  short* x     = (short*)(ws + (41ull<<20));     // 16MiB: 41..57; reused as vt
  short* wab   = (short*)(ws + (57ull<<20));     // 16MiB: 57..73
  short* ve    = (short*)(ws + (73ull<<20));     // 16MiB: 73..89; dead after k_vt
  short* pbuf  = (short*)(ws + (89ull<<20));     // 64MiB: 89..153 (all 8 batches)
  short* ke = g; short* vt = x;

  float* res  = (float*)d_out;
  float* attn = (float*)d_out + (size_t)ROWS*DP;

  k_knn  <<<ROWS/4, 256, 0, stream>>>(xyz, kidx, kw, wsum);
  k_prep2<<<(4*DM*DM + 2*DM*DP + ROWS*DP)/256, 256, 0, stream>>>(
           Wq, Wk, Wv, Wd2, W1, W2, feat, Wqt, Wkt, Wvt, Wd2t, W1t, W2t, featb);
  k_g    <<<ROWS/4, 256, 0, stream>>>(xyz, Wd1, bd1, kidx, kw, wsum, g);
  k_gemm<DP,0>  <<<dim3(ROWS/128, DM/128), 256, 0, stream>>>(featb, W1t, b1, nullptr, x);
  k_gemm64<0>   <<<dim3(ROWS/128, DM/128), 256, 0, stream>>>(g, Wd2t, bd2, nullptr, wab);
  k_gemm3       <<<dim3(ROWS/128, 6), 512, 0, stream>>>(x, Wqt, wab, qe, ke, ve);
  k_vt   <<<dim3(NN/32, DM/32, BB), 256, 0, stream>>>(ve, vt);
  // attention: single pass over all 8 batches (pbuf 64 MiB), BK=64, lsum fused into pv
  k_sexp <<<1024, 512, 0, stream>>>(qe, ke, pbuf, lsum_part);
  k_pv   <<<512, 512, 0, stream>>>(pbuf, vt, lsum_part, attn);
  k_res  <<<ROWS/64, 256, 0, stream>>>(attn, W2t, b2, feat, res);
}